// Round 6
// baseline (2269.930 us; speedup 1.0000x reference)
//
#include <hip/hip_runtime.h>

#define DD 512
#define MM 4
#define BB 4
#define SS 128
#define KK 32
#define NSTEPS 16
#define EPSF 1e-6f
#define SCALEF 0.04419417382415922f  // 512^-0.5
#define BMSD (BB * MM * SS * DD)

typedef unsigned short u16;
typedef __bf16 bf16x8 __attribute__((ext_vector_type(8)));
typedef u16 u16x8 __attribute__((ext_vector_type(8)));
typedef float f32x16 __attribute__((ext_vector_type(16)));
typedef unsigned int u32x4 __attribute__((ext_vector_type(4)));

__device__ inline void split_bf16(float x, u16& h, u16& l) {
  __bf16 hb = (__bf16)x;
  float hf = (float)hb;
  __bf16 lb = (__bf16)(x - hf);
  h = __builtin_bit_cast(u16, hb);
  l = __builtin_bit_cast(u16, lb);
}

// ---------------- weight fp32 -> split bf16 [row][1024] (hi | lo) ----------------
__global__ void k_convw(const float* __restrict__ src, u16* __restrict__ dst) {
  int idx = blockIdx.x * 256 + threadIdx.x;  // over M*D*D
  int row = idx >> 9, k = idx & 511;
  u16 h, l;
  split_bf16(src[idx], h, l);
  dst[(size_t)row * 1024 + k] = h;
  dst[(size_t)row * 1024 + 512 + k] = l;
}

// ---------------- tiny zero (flat buffer, one-time before k_init) ----------------
__global__ void k_zero(float* __restrict__ p) {
  p[blockIdx.x * 256 + threadIdx.x] = 0.f;
}

// ---------------- transpose-convert: fp32 [m][o][d] -> split bf16 [m*D+d][o hi|lo] ----------------
__global__ void k_convt(const float* __restrict__ src, u16* __restrict__ dst) {
  __shared__ float tile[64][65];
  int m = blockIdx.z;
  int o0 = blockIdx.y * 64, d0 = blockIdx.x * 64;
  int tid = threadIdx.x;  // 256
  int g = tid >> 6, lane = tid & 63;
#pragma unroll
  for (int i = 0; i < 16; i++) {
    int o_l = g * 16 + i;
    tile[o_l][lane] = src[(size_t)(m * 512 + o0 + o_l) * 512 + d0 + lane];
  }
  __syncthreads();
#pragma unroll
  for (int i = 0; i < 16; i++) {
    int d_l = g * 16 + i;
    float v = tile[lane][d_l];
    u16 h, l;
    split_bf16(v, h, l);
    size_t drow = (size_t)(m * 512 + d0 + d_l) * 1024;
    dst[drow + o0 + lane] = h;
    dst[drow + 512 + o0 + lane] = l;
  }
}

// ---------------- init (also seeds flat(0) via atomics; flat pre-zeroed) ----------------
__global__ void k_init(const float* __restrict__ xr, const float* __restrict__ xi,
                       float* __restrict__ sr, float* __restrict__ si,
                       float* __restrict__ acc, float* __restrict__ memv,
                       float* __restrict__ ptrv, float* __restrict__ rem2,
                       u16* __restrict__ crbf, u16* __restrict__ cibf,
                       float* __restrict__ flat) {
  int idx = blockIdx.x * 256 + threadIdx.x;
  if (idx < BB * SS * 2 * DD) acc[idx] = 0.f;
  if (idx < BB * SS * DD) {
    float a = xr[idx], b = xi[idx];
    sr[idx] = a; si[idx] = b;
    int row = idx >> 9, d = idx & 511;
    u16 h, l;
    split_bf16(a, h, l);   // c0 = 0.5x + 0.5x = x
    crbf[(size_t)row * 1024 + d] = h;
    crbf[(size_t)row * 1024 + 512 + d] = l;
    split_bf16(b, h, l);
    cibf[(size_t)row * 1024 + d] = h;
    cibf[(size_t)row * 1024 + 512 + d] = l;
    int bb = idx >> 16;  // / (S*D)
    atomicAdd(&flat[bb * 2 * DD + d], a * (1.0f / SS));
    atomicAdd(&flat[bb * 2 * DD + DD + d], b * (1.0f / SS));
  }
  if (idx < BB * KK * 2 * DD) memv[idx] = 0.f;
  if (idx < BB * KK) ptrv[idx] = ((idx & (KK - 1)) == 0) ? 1.f : 0.f;
  if (idx < 2 * BB) rem2[idx] = 1.f;
}

// ---------------- k_stack: ctrl softmax + ptr update + mem update/read + st finalize ----------------
// One block per b, 512 threads. Reads flat (mean of prev-step s, built by combine atomics),
// zeroes it for next step's accumulation. Also zeroes head accumulators for this step.
__global__ __launch_bounds__(512) void k_stack(
    float* __restrict__ flat,
    const float* __restrict__ ctrl_w, const float* __restrict__ ctrl_b,
    float* __restrict__ ptrv,
    float* __restrict__ memv, float* __restrict__ readv,
    const float* __restrict__ st_score_w, const float* __restrict__ st_conf_w,
    const float* __restrict__ st_score_b, const float* __restrict__ st_conf_b,
    float* __restrict__ stv,
    float* __restrict__ scorev, float* __restrict__ confv, float* __restrict__ haltv) {
  int b = blockIdx.x;
  int tid = threadIdx.x;  // 512
  __shared__ float red[3 * 512];
  __shared__ float ctrl[3], optr[KK], nptr_s[KK], wm_s[KK], normf;

  // zero head accumulators for this b (pv accumulates atomically later this step)
  int hr = b * MM * SS + tid;
  scorev[hr] = 0.f; confv[hr] = 0.f; haltv[hr] = 0.f;

  if (tid < KK) optr[tid] = ptrv[b * KK + tid];

  float f0 = flat[b * 2 * DD + tid];
  float f1 = flat[b * 2 * DD + 512 + tid];
  flat[b * 2 * DD + tid] = 0.f;        // ready for combine(t)'s accumulation
  flat[b * 2 * DD + 512 + tid] = 0.f;

  float d0 = f0 * ctrl_w[tid * 3 + 0] + f1 * ctrl_w[(512 + tid) * 3 + 0];
  float d1 = f0 * ctrl_w[tid * 3 + 1] + f1 * ctrl_w[(512 + tid) * 3 + 1];
  float d2 = f0 * ctrl_w[tid * 3 + 2] + f1 * ctrl_w[(512 + tid) * 3 + 2];
  red[tid] = d0; red[512 + tid] = d1; red[1024 + tid] = d2;
  __syncthreads();
  for (int off = 256; off > 0; off >>= 1) {
    if (tid < off) {
      red[tid] += red[tid + off];
      red[512 + tid] += red[512 + tid + off];
      red[1024 + tid] += red[1024 + tid + off];
    }
    __syncthreads();
  }
  if (tid == 0) {
    float l0 = red[0] + ctrl_b[0], l1 = red[512] + ctrl_b[1], l2 = red[1024] + ctrl_b[2];
    float mx = fmaxf(l0, fmaxf(l1, l2));
    float e0 = expf(l0 - mx), e1 = expf(l1 - mx), e2 = expf(l2 - mx);
    float s = e0 + e1 + e2;
    ctrl[0] = e0 / s; ctrl[1] = e1 / s; ctrl[2] = e2 / s;
  }
  __syncthreads();
  if (tid < KK) {
    float up = optr[(tid + KK - 1) & (KK - 1)];
    float dn = optr[(tid + 1) & (KK - 1)];
    nptr_s[tid] = ctrl[0] * up + ctrl[1] * dn + ctrl[2] * optr[tid];
    wm_s[tid] = ctrl[0] * up;
  }
  __syncthreads();
  if (tid == 0) {
    float s = 0.f;
    for (int k = 0; k < KK; k++) s += nptr_s[k];
    normf = 1.f / (s + EPSF);
  }
  __syncthreads();
  if (tid < KK) {
    float np = nptr_s[tid] * normf;
    nptr_s[tid] = np;
    ptrv[b * KK + tid] = np;
  }
  __syncthreads();

  // mem update + read; thread handles e = tid and e = tid+512
  float racc0 = 0.f, racc1 = 0.f;
#pragma unroll 4
  for (int k = 0; k < KK; k++) {
    size_t idx = ((size_t)(b * KK + k)) * 2 * DD;
    float wmk = wm_s[k], np = nptr_s[k];
    float m0 = memv[idx + tid], m1 = memv[idx + 512 + tid];
    float n0 = wmk * f0 + m0 * (1.f - wmk);
    float n1 = wmk * f1 + m1 * (1.f - wmk);
    memv[idx + tid] = n0; memv[idx + 512 + tid] = n1;
    racc0 += n0 * np; racc1 += n1 * np;
  }
  readv[b * 2 * DD + tid] = racc0;
  readv[b * 2 * DD + 512 + tid] = racc1;
  float rs = racc0 * st_score_w[tid] + racc1 * st_score_w[512 + tid];
  float rc = racc0 * st_conf_w[tid] + racc1 * st_conf_w[512 + tid];
  red[tid] = rs; red[512 + tid] = rc;
  __syncthreads();
  for (int off = 256; off > 0; off >>= 1) {
    if (tid < off) { red[tid] += red[tid + off]; red[512 + tid] += red[512 + tid + off]; }
    __syncthreads();
  }
  if (tid == 0) {
    stv[b] = red[0] + st_score_b[0];
    stv[BB + b] = 1.f / (1.f + expf(-(red[512] + st_conf_b[0])));
  }
}

#define LSTR 72  // LDS row stride in bf16 elems

// ---------------- Wl complex NT GEMM, split-K x2 (even/odd chunks), fp32 partials ----------------
__global__ __launch_bounds__(256) void k_gemm_mfma(
    const u16* __restrict__ Ar, const u16* __restrict__ Ai,
    const u16* __restrict__ Wr, const u16* __restrict__ Wi,
    float* __restrict__ Cr, float* __restrict__ Ci) {
  __shared__ u16 sAr[64][LSTR], sAi[64][LSTR], sWr[64][LSTR], sWi[64][LSTR];
  int mz = blockIdx.z;
  int m = mz & (MM - 1), split = mz >> 2;
  int row_blk = blockIdx.y * 64, o_blk = blockIdx.x * 64;
  int tid = threadIdx.x;

  int lrow = tid >> 3, lk8 = (tid & 7) << 3;
  size_t arow0 = (size_t)(row_blk + lrow), arow1 = arow0 + 32;  // dense b*S+s rows
  size_t wrow0 = (size_t)m * DD + o_blk + lrow, wrow1 = wrow0 + 32;

  int wave = tid >> 6, lane = tid & 63;
  int wrow = (wave >> 1) * 32, wcol = (wave & 1) * 32;
  int l31 = lane & 31, khalf = (lane >> 5) * 8;

  f32x16 accP, accN, accI;
  for (int i = 0; i < 16; i++) { accP[i] = 0.f; accN[i] = 0.f; accI[i] = 0.f; }

  int it20 = split;
  int seg0 = it20 >> 3, k00 = (it20 & 7) * 64;
  int aofs0 = (seg0 == 1) ? 512 : 0, wofs0 = (seg0 == 2) ? 512 : 0;
  u16x8 g0 = *(const u16x8*)&Ar[arow0 * 1024 + aofs0 + k00 + lk8];
  u16x8 g1 = *(const u16x8*)&Ar[arow1 * 1024 + aofs0 + k00 + lk8];
  u16x8 g2 = *(const u16x8*)&Ai[arow0 * 1024 + aofs0 + k00 + lk8];
  u16x8 g3 = *(const u16x8*)&Ai[arow1 * 1024 + aofs0 + k00 + lk8];
  u16x8 g4 = *(const u16x8*)&Wr[wrow0 * 1024 + wofs0 + k00 + lk8];
  u16x8 g5 = *(const u16x8*)&Wr[wrow1 * 1024 + wofs0 + k00 + lk8];
  u16x8 g6 = *(const u16x8*)&Wi[wrow0 * 1024 + wofs0 + k00 + lk8];
  u16x8 g7 = *(const u16x8*)&Wi[wrow1 * 1024 + wofs0 + k00 + lk8];

  for (int jt = 0; jt < 12; ++jt) {
    __syncthreads();  // prev iter's LDS reads complete
    *(u16x8*)&sAr[lrow][lk8] = g0;
    *(u16x8*)&sAr[lrow + 32][lk8] = g1;
    *(u16x8*)&sAi[lrow][lk8] = g2;
    *(u16x8*)&sAi[lrow + 32][lk8] = g3;
    *(u16x8*)&sWr[lrow][lk8] = g4;
    *(u16x8*)&sWr[lrow + 32][lk8] = g5;
    *(u16x8*)&sWi[lrow][lk8] = g6;
    *(u16x8*)&sWi[lrow + 32][lk8] = g7;
    u16x8 n0, n1, n2, n3, n4, n5, n6, n7;
    if (jt < 11) {
      int it2 = 2 * (jt + 1) + split, seg = it2 >> 3, k0 = (it2 & 7) * 64;
      int aofs = (seg == 1) ? 512 : 0, wofs = (seg == 2) ? 512 : 0;
      n0 = *(const u16x8*)&Ar[arow0 * 1024 + aofs + k0 + lk8];
      n1 = *(const u16x8*)&Ar[arow1 * 1024 + aofs + k0 + lk8];
      n2 = *(const u16x8*)&Ai[arow0 * 1024 + aofs + k0 + lk8];
      n3 = *(const u16x8*)&Ai[arow1 * 1024 + aofs + k0 + lk8];
      n4 = *(const u16x8*)&Wr[wrow0 * 1024 + wofs + k0 + lk8];
      n5 = *(const u16x8*)&Wr[wrow1 * 1024 + wofs + k0 + lk8];
      n6 = *(const u16x8*)&Wi[wrow0 * 1024 + wofs + k0 + lk8];
      n7 = *(const u16x8*)&Wi[wrow1 * 1024 + wofs + k0 + lk8];
    }
    __syncthreads();
#pragma unroll
    for (int kk = 0; kk < 64; kk += 16) {
      bf16x8 fAr = *(const bf16x8*)&sAr[wrow + l31][kk + khalf];
      bf16x8 fAi = *(const bf16x8*)&sAi[wrow + l31][kk + khalf];
      bf16x8 fWr = *(const bf16x8*)&sWr[wcol + l31][kk + khalf];
      bf16x8 fWi = *(const bf16x8*)&sWi[wcol + l31][kk + khalf];
      accP = __builtin_amdgcn_mfma_f32_32x32x16_bf16(fAr, fWr, accP, 0, 0, 0);
      accN = __builtin_amdgcn_mfma_f32_32x32x16_bf16(fAi, fWi, accN, 0, 0, 0);
      accI = __builtin_amdgcn_mfma_f32_32x32x16_bf16(fAi, fWr, accI, 0, 0, 0);
      accI = __builtin_amdgcn_mfma_f32_32x32x16_bf16(fAr, fWi, accI, 0, 0, 0);
    }
    if (jt < 11) {
      g0 = n0; g1 = n1; g2 = n2; g3 = n3; g4 = n4; g5 = n5; g6 = n6; g7 = n7;
    }
  }

  int o = o_blk + wcol + l31;
  size_t sofs = (size_t)split * BMSD;
#pragma unroll
  for (int reg = 0; reg < 16; reg++) {
    int r_in = (reg & 3) + 8 * (reg >> 2) + 4 * (lane >> 5);
    int gr = row_blk + wrow + r_in;
    int b = gr >> 7, s = gr & (SS - 1);
    size_t crow = (size_t)((b * MM + m) * SS + s);
    Cr[sofs + crow * DD + o] = accP[reg] - accN[reg];
    Ci[sofs + crow * DD + o] = accI[reg];
  }
}

// ---------------- one-time: H[e,d] = sum_o conj(WkT[e,o]) * WqT[d,o]  (fp32 out) ----------------
__global__ __launch_bounds__(256) void k_gemm_g(
    const u16* __restrict__ Ar, const u16* __restrict__ Ai,
    const u16* __restrict__ Wr, const u16* __restrict__ Wi,
    float* __restrict__ Hr, float* __restrict__ Hi) {
  __shared__ u16 sAr[64][LSTR], sAi[64][LSTR], sWr[64][LSTR], sWi[64][LSTR];
  int m = blockIdx.z;
  int row_blk = blockIdx.y * 64, o_blk = blockIdx.x * 64;
  int tid = threadIdx.x;

  int lrow = tid >> 3, lk8 = (tid & 7) << 3;
  size_t arow0 = (size_t)(m * 512 + row_blk + lrow), arow1 = arow0 + 32;
  size_t wrow0 = (size_t)(m * 512 + o_blk + lrow), wrow1 = wrow0 + 32;

  int wave = tid >> 6, lane = tid & 63;
  int wrow = (wave >> 1) * 32, wcol = (wave & 1) * 32;
  int l31 = lane & 31, khalf = (lane >> 5) * 8;

  f32x16 accP, accN, accI;
  for (int i = 0; i < 16; i++) { accP[i] = 0.f; accN[i] = 0.f; accI[i] = 0.f; }

  u16x8 g0 = *(const u16x8*)&Ar[arow0 * 1024 + lk8];
  u16x8 g1 = *(const u16x8*)&Ar[arow1 * 1024 + lk8];
  u16x8 g2 = *(const u16x8*)&Ai[arow0 * 1024 + lk8];
  u16x8 g3 = *(const u16x8*)&Ai[arow1 * 1024 + lk8];
  u16x8 g4 = *(const u16x8*)&Wr[wrow0 * 1024 + lk8];
  u16x8 g5 = *(const u16x8*)&Wr[wrow1 * 1024 + lk8];
  u16x8 g6 = *(const u16x8*)&Wi[wrow0 * 1024 + lk8];
  u16x8 g7 = *(const u16x8*)&Wi[wrow1 * 1024 + lk8];

  for (int it = 0; it < 24; ++it) {
    __syncthreads();
    *(u16x8*)&sAr[lrow][lk8] = g0;
    *(u16x8*)&sAr[lrow + 32][lk8] = g1;
    *(u16x8*)&sAi[lrow][lk8] = g2;
    *(u16x8*)&sAi[lrow + 32][lk8] = g3;
    *(u16x8*)&sWr[lrow][lk8] = g4;
    *(u16x8*)&sWr[lrow + 32][lk8] = g5;
    *(u16x8*)&sWi[lrow][lk8] = g6;
    *(u16x8*)&sWi[lrow + 32][lk8] = g7;
    u16x8 n0, n1, n2, n3, n4, n5, n6, n7;
    if (it < 23) {
      int it2 = it + 1, seg = it2 >> 3, k0 = (it2 & 7) * 64;
      int aofs = (seg == 1) ? 512 : 0, wofs = (seg == 2) ? 512 : 0;
      n0 = *(const u16x8*)&Ar[arow0 * 1024 + aofs + k0 + lk8];
      n1 = *(const u16x8*)&Ar[arow1 * 1024 + aofs + k0 + lk8];
      n2 = *(const u16x8*)&Ai[arow0 * 1024 + aofs + k0 + lk8];
      n3 = *(const u16x8*)&Ai[arow1 * 1024 + aofs + k0 + lk8];
      n4 = *(const u16x8*)&Wr[wrow0 * 1024 + wofs + k0 + lk8];
      n5 = *(const u16x8*)&Wr[wrow1 * 1024 + wofs + k0 + lk8];
      n6 = *(const u16x8*)&Wi[wrow0 * 1024 + wofs + k0 + lk8];
      n7 = *(const u16x8*)&Wi[wrow1 * 1024 + wofs + k0 + lk8];
    }
    __syncthreads();
#pragma unroll
    for (int kk = 0; kk < 64; kk += 16) {
      bf16x8 fAr = *(const bf16x8*)&sAr[wrow + l31][kk + khalf];
      bf16x8 fAi = *(const bf16x8*)&sAi[wrow + l31][kk + khalf];
      bf16x8 fWr = *(const bf16x8*)&sWr[wcol + l31][kk + khalf];
      bf16x8 fWi = *(const bf16x8*)&sWi[wcol + l31][kk + khalf];
      u32x4 t = __builtin_bit_cast(u32x4, fAi) ^ 0x80008000u;
      bf16x8 nAi = __builtin_bit_cast(bf16x8, t);
      accP = __builtin_amdgcn_mfma_f32_32x32x16_bf16(fAr, fWr, accP, 0, 0, 0);
      accN = __builtin_amdgcn_mfma_f32_32x32x16_bf16(fAi, fWi, accN, 0, 0, 0);
      accI = __builtin_amdgcn_mfma_f32_32x32x16_bf16(fAr, fWi, accI, 0, 0, 0);
      accI = __builtin_amdgcn_mfma_f32_32x32x16_bf16(nAi, fWr, accI, 0, 0, 0);
    }
    if (it < 23) {
      g0 = n0; g1 = n1; g2 = n2; g3 = n3; g4 = n4; g5 = n5; g6 = n6; g7 = n7;
    }
  }

  int o = o_blk + wcol + l31;
#pragma unroll
  for (int reg = 0; reg < 16; reg++) {
    int r_in = (reg & 3) + 8 * (reg >> 2) + 4 * (lane >> 5);
    int gr = row_blk + wrow + r_in;          // e in [0,512)
    size_t crow = (size_t)(m * 512 + gr);
    Hr[crow * DD + o] = accP[reg] + accN[reg];
    Hi[crow * DD + o] = accI[reg];
  }
}

// ---------------- merged Y/V GEMM (K GEMM eliminated via H folding) ----------------
__global__ __launch_bounds__(256) void k_gemm_qkv(
    const u16* __restrict__ Ar, const u16* __restrict__ Ai,
    const u16* __restrict__ wbf, size_t WSLOT,
    u16* __restrict__ qbr, u16* __restrict__ qbi,
    u16* __restrict__ vbr, u16* __restrict__ vbi) {
  __shared__ u16 sAr[64][LSTR], sAi[64][LSTR], sWr[64][LSTR], sWi[64][LSTR];
  int zid = blockIdx.z;
  int m = zid >> 1, w = zid & 1;                 // w=0: Y (H slot 8), w=1: V (Wv slot 6)
  int slot = (w == 0) ? 8 : 6;
  const u16* Wr = wbf + (size_t)slot * WSLOT;
  const u16* Wi = Wr + WSLOT;
  int row_blk = blockIdx.y * 64, o_blk = blockIdx.x * 64;
  int tid = threadIdx.x;

  int lrow = tid >> 3, lk8 = (tid & 7) << 3;
  int gr0 = row_blk + lrow, gr1 = gr0 + 32;
  size_t arow0 = (size_t)(((gr0 >> 7) * MM + m) * SS + (gr0 & (SS - 1)));
  size_t arow1 = (size_t)(((gr1 >> 7) * MM + m) * SS + (gr1 & (SS - 1)));
  size_t wrow0 = (size_t)m * DD + o_blk + lrow, wrow1 = wrow0 + 32;

  int wave = tid >> 6, lane = tid & 63;
  int wrow = (wave >> 1) * 32, wcol = (wave & 1) * 32;
  int l31 = lane & 31, khalf = (lane >> 5) * 8;

  f32x16 accP, accN, accI;
  for (int i = 0; i < 16; i++) { accP[i] = 0.f; accN[i] = 0.f; accI[i] = 0.f; }

  u16x8 g0 = *(const u16x8*)&Ar[arow0 * 1024 + lk8];
  u16x8 g1 = *(const u16x8*)&Ar[arow1 * 1024 + lk8];
  u16x8 g2 = *(const u16x8*)&Ai[arow0 * 1024 + lk8];
  u16x8 g3 = *(const u16x8*)&Ai[arow1 * 1024 + lk8];
  u16x8 g4 = *(const u16x8*)&Wr[wrow0 * 1024 + lk8];
  u16x8 g5 = *(const u16x8*)&Wr[wrow1 * 1024 + lk8];
  u16x8 g6 = *(const u16x8*)&Wi[wrow0 * 1024 + lk8];
  u16x8 g7 = *(const u16x8*)&Wi[wrow1 * 1024 + lk8];

  for (int it = 0; it < 24; ++it) {
    __syncthreads();
    *(u16x8*)&sAr[lrow][lk8] = g0;
    *(u16x8*)&sAr[lrow + 32][lk8] = g1;
    *(u16x8*)&sAi[lrow][lk8] = g2;
    *(u16x8*)&sAi[lrow + 32][lk8] = g3;
    *(u16x8*)&sWr[lrow][lk8] = g4;
    *(u16x8*)&sWr[lrow + 32][lk8] = g5;
    *(u16x8*)&sWi[lrow][lk8] = g6;
    *(u16x8*)&sWi[lrow + 32][lk8] = g7;
    u16x8 n0, n1, n2, n3, n4, n5, n6, n7;
    if (it < 23) {
      int it2 = it + 1, seg = it2 >> 3, k0 = (it2 & 7) * 64;
      int aofs = (seg == 1) ? 512 : 0, wofs = (seg == 2) ? 512 : 0;
      n0 = *(const u16x8*)&Ar[arow0 * 1024 + aofs + k0 + lk8];
      n1 = *(const u16x8*)&Ar[arow1 * 1024 + aofs + k0 + lk8];
      n2 = *(const u16x8*)&Ai[arow0 * 1024 + aofs + k0 + lk8];
      n3 = *(const u16x8*)&Ai[arow1 * 1024 + aofs + k0 + lk8];
      n4 = *(const u16x8*)&Wr[wrow0 * 1024 + wofs + k0 + lk8];
      n5 = *(const u16x8*)&Wr[wrow1 * 1024 + wofs + k0 + lk8];
      n6 = *(const u16x8*)&Wi[wrow0 * 1024 + wofs + k0 + lk8];
      n7 = *(const u16x8*)&Wi[wrow1 * 1024 + wofs + k0 + lk8];
    }
    __syncthreads();
#pragma unroll
    for (int kk = 0; kk < 64; kk += 16) {
      bf16x8 fAr = *(const bf16x8*)&sAr[wrow + l31][kk + khalf];
      bf16x8 fAi = *(const bf16x8*)&sAi[wrow + l31][kk + khalf];
      bf16x8 fWr = *(const bf16x8*)&sWr[wcol + l31][kk + khalf];
      bf16x8 fWi = *(const bf16x8*)&sWi[wcol + l31][kk + khalf];
      accP = __builtin_amdgcn_mfma_f32_32x32x16_bf16(fAr, fWr, accP, 0, 0, 0);
      accN = __builtin_amdgcn_mfma_f32_32x32x16_bf16(fAi, fWi, accN, 0, 0, 0);
      accI = __builtin_amdgcn_mfma_f32_32x32x16_bf16(fAi, fWr, accI, 0, 0, 0);
      accI = __builtin_amdgcn_mfma_f32_32x32x16_bf16(fAr, fWi, accI, 0, 0, 0);
    }
    if (it < 23) {
      g0 = n0; g1 = n1; g2 = n2; g3 = n3; g4 = n4; g5 = n5; g6 = n6; g7 = n7;
    }
  }

  u16* Cr = (w == 0) ? qbr : vbr;
  u16* Ci = (w == 0) ? qbi : vbi;
  int o = o_blk + wcol + l31;
#pragma unroll
  for (int reg = 0; reg < 16; reg++) {
    int r_in = (reg & 3) + 8 * (reg >> 2) + 4 * (lane >> 5);
    int gr = row_blk + wrow + r_in;
    int b = gr >> 7, s = gr & (SS - 1);
    size_t crow = (size_t)((b * MM + m) * SS + s);
    u16 h, l;
    split_bf16(accP[reg] - accN[reg], h, l);
    Cr[crow * 1024 + o] = h;
    Cr[crow * 1024 + 512 + o] = l;
    split_bf16(accI[reg], h, l);
    Ci[crow * 1024 + o] = h;
    Ci[crow * 1024 + 512 + o] = l;
  }
}

// ---------------- scores + fused softmax -> split P (reg-prefetch pipelined) ----------------
// Q inputs = Y buffers; K inputs = z buffers (H-folded attention).
__global__ __launch_bounds__(256) void k_scores_sm(
    const u16* __restrict__ Q_r, const u16* __restrict__ Q_i,
    const u16* __restrict__ K_r, const u16* __restrict__ K_i,
    u16* __restrict__ Pb) {
  __shared__ __align__(16) char smem[55296];  // 54 KB
  u16 (*sQr)[LSTR] = (u16(*)[LSTR])smem;                  // 64 rows
  u16 (*sQi)[LSTR] = (u16(*)[LSTR])(smem + 9216);         // 64 rows
  u16 (*sKr)[LSTR] = (u16(*)[LSTR])(smem + 18432);        // 128 rows
  u16 (*sKi)[LSTR] = (u16(*)[LSTR])(smem + 36864);        // 128 rows
  float (*stile)[132] = (float(*)[132])smem;              // 64 x 132 overlay (33792 B)

  int bm = blockIdx.z;
  int s_blk = blockIdx.y * 64;
  int tid = threadIdx.x;
  int lrow = tid >> 3, lk8 = (tid & 7) << 3;
  size_t qrow0 = (size_t)(bm * SS + s_blk + lrow), qrow1 = qrow0 + 32;
  size_t krow = (size_t)(bm * SS + lrow);  // +0,32,64,96

  int wave = tid >> 6, lane = tid & 63;
  int srow_w = (wave & 1) * 32;
  int tcol_w = (wave >> 1) * 64;
  int l31 = lane & 31, khalf = (lane >> 5) * 8;

  f32x16 acc0, acc1;
  for (int i = 0; i < 16; i++) { acc0[i] = 0.f; acc1[i] = 0.f; }

  // prologue loads (it=0)
  u16x8 pf[12];
  pf[0] = *(const u16x8*)&Q_r[qrow0 * 1024 + lk8];
  pf[1] = *(const u16x8*)&Q_r[qrow1 * 1024 + lk8];
  pf[2] = *(const u16x8*)&Q_i[qrow0 * 1024 + lk8];
  pf[3] = *(const u16x8*)&Q_i[qrow1 * 1024 + lk8];
#pragma unroll
  for (int q = 0; q < 4; q++) {
    pf[4 + q] = *(const u16x8*)&K_r[(krow + q * 32) * 1024 + lk8];
    pf[8 + q] = *(const u16x8*)&K_i[(krow + q * 32) * 1024 + lk8];
  }

  for (int it = 0; it < 24; ++it) {
    __syncthreads();  // prev iter's LDS reads complete
    *(u16x8*)&sQr[lrow][lk8] = pf[0];
    *(u16x8*)&sQr[lrow + 32][lk8] = pf[1];
    *(u16x8*)&sQi[lrow][lk8] = pf[2];
    *(u16x8*)&sQi[lrow + 32][lk8] = pf[3];
#pragma unroll
    for (int q = 0; q < 4; q++) {
      *(u16x8*)&sKr[lrow + q * 32][lk8] = pf[4 + q];
      *(u16x8*)&sKi[lrow + q * 32][lk8] = pf[8 + q];
    }
    // issue next iter's loads BEFORE compute
    u16x8 nf[12];
    if (it < 23) {
      int it2 = it + 1, seg = it2 >> 3, k0 = (it2 & 7) * 64;
      int qofs = (seg == 1) ? 512 : 0;
      int kofs = (seg == 2) ? 512 : 0;
      nf[0] = *(const u16x8*)&Q_r[qrow0 * 1024 + qofs + k0 + lk8];
      nf[1] = *(const u16x8*)&Q_r[qrow1 * 1024 + qofs + k0 + lk8];
      nf[2] = *(const u16x8*)&Q_i[qrow0 * 1024 + qofs + k0 + lk8];
      nf[3] = *(const u16x8*)&Q_i[qrow1 * 1024 + qofs + k0 + lk8];
#pragma unroll
      for (int q = 0; q < 4; q++) {
        nf[4 + q] = *(const u16x8*)&K_r[(krow + q * 32) * 1024 + kofs + k0 + lk8];
        nf[8 + q] = *(const u16x8*)&K_i[(krow + q * 32) * 1024 + kofs + k0 + lk8];
      }
    }
    __syncthreads();
#pragma unroll
    for (int kk = 0; kk < 64; kk += 16) {
      bf16x8 fQr = *(const bf16x8*)&sQr[srow_w + l31][kk + khalf];
      bf16x8 fQi = *(const bf16x8*)&sQi[srow_w + l31][kk + khalf];
      bf16x8 fKr0 = *(const bf16x8*)&sKr[tcol_w + l31][kk + khalf];
      bf16x8 fKr1 = *(const bf16x8*)&sKr[tcol_w + 32 + l31][kk + khalf];
      bf16x8 fKi0 = *(const bf16x8*)&sKi[tcol_w + l31][kk + khalf];
      bf16x8 fKi1 = *(const bf16x8*)&sKi[tcol_w + 32 + l31][kk + khalf];
      acc0 = __builtin_amdgcn_mfma_f32_32x32x16_bf16(fQr, fKr0, acc0, 0, 0, 0);
      acc0 = __builtin_amdgcn_mfma_f32_32x32x16_bf16(fQi, fKi0, acc0, 0, 0, 0);
      acc1 = __builtin_amdgcn_mfma_f32_32x32x16_bf16(fQr, fKr1, acc1, 0, 0, 0);
      acc1 = __builtin_amdgcn_mfma_f32_32x32x16_bf16(fQi, fKi1, acc1, 0, 0, 0);
    }
    if (it < 23) {
#pragma unroll
      for (int j = 0; j < 12; j++) pf[j] = nf[j];
    }
  }

  // ---- fused softmax over full 128-col rows ----
  __syncthreads();  // staging tiles dead; overlay stile
#pragma unroll
  for (int reg = 0; reg < 16; reg++) {
    int r = srow_w + (reg & 3) + 8 * (reg >> 2) + 4 * (lane >> 5);
    stile[r][tcol_w + l31] = acc0[reg] * SCALEF;
    stile[r][tcol_w + 32 + l31] = acc1[reg] * SCALEF;
  }
  __syncthreads();
  int row = tid >> 2;          // 0..63
  int quarter = tid & 3;       // cols quarter*32..+31
  float mx = -3.4e38f;
#pragma unroll
  for (int j = 0; j < 32; j++) mx = fmaxf(mx, stile[row][quarter * 32 + j]);
  mx = fmaxf(mx, __shfl_xor(mx, 1));
  mx = fmaxf(mx, __shfl_xor(mx, 2));
  float ev[32];
  float sum = 0.f;
#pragma unroll
  for (int j = 0; j < 32; j++) {
    ev[j] = expf(stile[row][quarter * 32 + j] - mx);
    sum += ev[j];
  }
  sum += __shfl_xor(sum, 1);
  sum += __shfl_xor(sum, 2);
  float inv = 1.f / sum;
  size_t prow = (size_t)(bm * SS + s_blk + row) * 256;
#pragma unroll
  for (int j = 0; j < 32; j++) {
    int c = quarter * 32 + j;
    u16 h, l;
    split_bf16(ev[j] * inv, h, l);
    Pb[prow + c] = h;
    Pb[prow + 128 + c] = l;
  }
}

// ---------------- P x V MFMA + gate -> pr/pi fp32, FUSED score/conf/halt head dots ----------------
__global__ __launch_bounds__(256) void k_pv(
    const u16* __restrict__ Pb, const u16* __restrict__ vbr, const u16* __restrict__ vbi,
    const float* __restrict__ gate_mask,
    const float* __restrict__ score_w, const float* __restrict__ conf_w,
    const float* __restrict__ halt_w,
    float* __restrict__ pr, float* __restrict__ pi,
    float* __restrict__ scorev, float* __restrict__ confv, float* __restrict__ haltv) {
  __shared__ u16 sP[64][LSTR], sVr[64][LSTR], sVi[64][LSTR];
  int bm = blockIdx.z;
  int m = bm & (MM - 1);
  int s_blk = blockIdx.y * 64;
  int o_blk = blockIdx.x * 64;
  int tid = threadIdx.x;
  int lrow = tid >> 3, lk8 = (tid & 7) << 3;
  size_t prow0 = (size_t)(bm * SS + s_blk + lrow), prow1 = prow0 + 32;

  int wave = tid >> 6, lane = tid & 63;
  int wrow = (wave >> 1) * 32;   // s
  int wcol = (wave & 1) * 32;    // d
  int l31 = lane & 31, khalf = (lane >> 5) * 8;

  f32x16 accR, accI;
  for (int i = 0; i < 16; i++) { accR[i] = 0.f; accI[i] = 0.f; }

  for (int it = 0; it < 6; ++it) {
    int seg = it >> 1, k0 = (it & 1) * 64;        // t-chunk
    int pofs = (seg == 1) ? 128 : 0;              // P lo half for seg1
    int vofs = (seg == 2) ? 512 : 0;              // V lo half for seg2
    u16x8 p0 = *(const u16x8*)&Pb[prow0 * 256 + pofs + k0 + lk8];
    u16x8 p1 = *(const u16x8*)&Pb[prow1 * 256 + pofs + k0 + lk8];
    size_t vrow0 = (size_t)(bm * SS + k0 + lrow), vrow1 = vrow0 + 32;
    u16x8 v0 = *(const u16x8*)&vbr[vrow0 * 1024 + vofs + o_blk + lk8];
    u16x8 v1 = *(const u16x8*)&vbr[vrow1 * 1024 + vofs + o_blk + lk8];
    u16x8 w0 = *(const u16x8*)&vbi[vrow0 * 1024 + vofs + o_blk + lk8];
    u16x8 w1 = *(const u16x8*)&vbi[vrow1 * 1024 + vofs + o_blk + lk8];
    __syncthreads();
    *(u16x8*)&sP[lrow][lk8] = p0;
    *(u16x8*)&sP[lrow + 32][lk8] = p1;
    *(u16x8*)&sVr[lrow][lk8] = v0;
    *(u16x8*)&sVr[lrow + 32][lk8] = v1;
    *(u16x8*)&sVi[lrow][lk8] = w0;
    *(u16x8*)&sVi[lrow + 32][lk8] = w1;
    __syncthreads();
#pragma unroll
    for (int kk = 0; kk < 64; kk += 16) {
      bf16x8 fP = *(const bf16x8*)&sP[wrow + l31][kk + khalf];
      u16x8 ar, ai;
#pragma unroll
      for (int j = 0; j < 8; j++) {
        ar[j] = sVr[kk + khalf + j][wcol + l31];  // transpose-on-read
        ai[j] = sVi[kk + khalf + j][wcol + l31];
      }
      accR = __builtin_amdgcn_mfma_f32_32x32x16_bf16(fP, __builtin_bit_cast(bf16x8, ar), accR, 0, 0, 0);
      accI = __builtin_amdgcn_mfma_f32_32x32x16_bf16(fP, __builtin_bit_cast(bf16x8, ai), accI, 0, 0, 0);
    }
  }

  int d = o_blk + wcol + l31;
  float g = 1.f / (1.f + expf(-gate_mask[m * DD + d]));
  // head weight slices for this (m, d)
  float swr = score_w[m * 2 * DD + d], swi = score_w[m * 2 * DD + DD + d];
  float cwr = conf_w[m * 2 * DD + d],  cwi = conf_w[m * 2 * DD + DD + d];
  float hwr = halt_w[m * 2 * DD + d],  hwi = halt_w[m * 2 * DD + DD + d];
#pragma unroll
  for (int reg = 0; reg < 16; reg++) {
    int r_in = (reg & 3) + 8 * (reg >> 2) + 4 * (lane >> 5);
    size_t crow = (size_t)(bm * SS + s_blk + wrow + r_in);
    float vR = accR[reg] * g, vI = accI[reg] * g;
    pr[crow * DD + d] = vR;
    pi[crow * DD + d] = vI;
    // per-row head dot partials over this wave's 32 d-lanes
    float ps = vR * swr + vI * swi;
    float pc = vR * cwr + vI * cwi;
    float ph = vR * hwr + vI * hwi;
#pragma unroll
    for (int off = 1; off < 32; off <<= 1) {
      ps += __shfl_xor(ps, off);
      pc += __shfl_xor(pc, off);
      ph += __shfl_xor(ph, off);
    }
    if (l31 == 0) {
      atomicAdd(&scorev[crow], ps);
      atomicAdd(&confv[crow], pc);
      atomicAdd(&haltv[crow], ph);
    }
  }
}

// ---------------- magnitude LN + phase renorm + mod scale -> split bf16 ----------------
// zr/zi carry TWO split-K partials at stride BMSD; summed here.
__global__ void k_lnphase(const float* __restrict__ zr, const float* __restrict__ zi,
                          const float* __restrict__ ln_scale, const float* __restrict__ ln_shift,
                          const float* __restrict__ mod_bias,
                          u16* __restrict__ zbr, u16* __restrict__ zbi) {
  int row = blockIdx.x;            // (b*M+m)*S + s
  int m = (row >> 7) & (MM - 1);
  int tid = threadIdx.x;           // 128
  size_t base = (size_t)row * DD;
  float zrv[4], ziv[4], rv[4];
  float sum = 0.f, sumsq = 0.f;
#pragma unroll
  for (int i = 0; i < 4; i++) {
    int o = tid + i * 128;
    float a = zr[base + o] + zr[(size_t)BMSD + base + o];
    float bv = zi[base + o] + zi[(size_t)BMSD + base + o];
    zrv[i] = a; ziv[i] = bv;
    float r = sqrtf(a * a + bv * bv);
    rv[i] = r;
    float mg = r + EPSF;
    sum += mg;
    sumsq += mg * mg;
  }
  __shared__ float rs[128], rq[128];
  rs[tid] = sum; rq[tid] = sumsq;
  __syncthreads();
  for (int off = 64; off > 0; off >>= 1) {
    if (tid < off) { rs[tid] += rs[tid + off]; rq[tid] += rq[tid + off]; }
    __syncthreads();
  }
  float mean = rs[0] * (1.0f / DD);
  float var = (rq[0] - (float)DD * mean * mean) * (1.0f / (DD - 1));
  float inv = 1.0f / sqrtf(var + EPSF);
#pragma unroll
  for (int i = 0; i < 4; i++) {
    int o = tid + i * 128;
    float mg = rv[i] + EPSF;
    float nm = (mg - mean) * inv * ln_scale[m * DD + o] + ln_shift[m * DD + o];
    float r = rv[i];
    float cosp, sinp;
    if (r > 0.f) { cosp = zrv[i] / r; sinp = ziv[i] / r; }
    else { cosp = 1.f; sinp = 0.f; }
    float z1r = nm * cosp, z1i = nm * sinp;
    float nrm = sqrtf(z1r * z1r + z1i * z1i) + EPSF;
    float sc = fmaxf(nrm + mod_bias[m * DD + o], 0.f) / nrm;
    u16 h, l;
    split_bf16(z1r * sc, h, l);
    zbr[(size_t)row * 1024 + o] = h;
    zbr[(size_t)row * 1024 + 512 + o] = l;
    split_bf16(z1i * sc, h, l);
    zbi[(size_t)row * 1024 + o] = h;
    zbi[(size_t)row * 1024 + 512 + o] = l;
  }
}

// ---------------- module-mix softmax + halt p + new state + acc + next-step c + flat accum ----------
// score/conf/halt inputs are raw dots; biases + sigmoid applied here. rem double-buffered by parity.
__global__ void k_combine(const float* __restrict__ pr, const float* __restrict__ pi,
                          const float* __restrict__ score, const float* __restrict__ conf,
                          const float* __restrict__ score_b, const float* __restrict__ conf_b,
                          const float* __restrict__ haltv, const float* __restrict__ halt_b,
                          const float* __restrict__ stv, const float* __restrict__ readv,
                          float* __restrict__ rem2, int parity,
                          const float* __restrict__ xr, const float* __restrict__ xi,
                          float* __restrict__ sr, float* __restrict__ si, float* __restrict__ acc,
                          u16* __restrict__ crbf, u16* __restrict__ cibf,
                          float* __restrict__ flat) {
  int bs = blockIdx.x;             // b*S + s
  int b = bs >> 7, s = bs & (SS - 1);
  int tid = threadIdx.x;           // 256
  __shared__ float w[5];
  __shared__ float cf_s;
  __shared__ float hred[256];

  // halt p reduction over (m, s): 512 raw dots for this b
  float hv = 0.f;
#pragma unroll
  for (int i = 0; i < 2; i++) {
    int j = tid + i * 256;
    float v = haltv[b * MM * SS + j] + halt_b[j >> 7];
    hv += 1.f / (1.f + expf(-v));
  }
  hred[tid] = hv;
  __syncthreads();
  for (int off = 128; off > 0; off >>= 1) {
    if (tid < off) hred[tid] += hred[tid + off];
    __syncthreads();
  }
  if (tid == 0) {
    float p = hred[0] * (1.0f / (MM * SS));
    float r = rem2[parity * BB + b];
    cf_s = p * r;
    if (s == 0) rem2[(parity ^ 1) * BB + b] = r * (1.f - p);
    float l[5];
    for (int m = 0; m < MM; m++) {
      int rr = (b * MM + m) * SS + s;
      float sc = score[rr] + score_b[m];
      float cfd = 1.f / (1.f + expf(-(conf[rr] + conf_b[m])));
      l[m] = sc * cfd;
    }
    l[4] = stv[b] * stv[BB + b];
    float mx = l[0];
    for (int j = 1; j < 5; j++) mx = fmaxf(mx, l[j]);
    float sum = 0.f;
    for (int j = 0; j < 5; j++) { l[j] = expf(l[j] - mx); sum += l[j]; }
    for (int j = 0; j < 5; j++) w[j] = l[j] / sum;
  }
  __syncthreads();
  float cf = cf_s;
#pragma unroll
  for (int i = 0; i < 2; i++) {
    int d = tid + i * 256;
    float nsr = w[4] * readv[b * 2 * DD + d];
    float nsi = w[4] * readv[b * 2 * DD + DD + d];
#pragma unroll
    for (int m = 0; m < MM; m++) {
      size_t off = ((size_t)((b * MM + m) * SS + s)) * DD + d;
      nsr += w[m] * pr[off];
      nsi += w[m] * pi[off];
    }
    size_t sidx = (size_t)bs * DD + d;
    sr[sidx] = nsr;
    si[sidx] = nsi;
    size_t aoff = (size_t)bs * 2 * DD;
    acc[aoff + d] += cf * nsr;
    acc[aoff + DD + d] += cf * nsi;
    u16 h, l;
    split_bf16(0.5f * xr[sidx] + 0.5f * nsr, h, l);
    crbf[(size_t)bs * 1024 + d] = h;
    crbf[(size_t)bs * 1024 + 512 + d] = l;
    split_bf16(0.5f * xi[sidx] + 0.5f * nsi, h, l);
    cibf[(size_t)bs * 1024 + d] = h;
    cibf[(size_t)bs * 1024 + 512 + d] = l;
    // accumulate next step's flat mean (flat zeroed by k_stack earlier this step)
    atomicAdd(&flat[b * 2 * DD + d], nsr * (1.0f / SS));
    atomicAdd(&flat[b * 2 * DD + DD + d], nsi * (1.0f / SS));
  }
}

// ---------------- out = acc + rem * concat(sr, si) ----------------
__global__ void k_final(const float* __restrict__ acc, const float* __restrict__ rem,
                        const float* __restrict__ sr, const float* __restrict__ si,
                        float* __restrict__ out) {
  int idx = blockIdx.x * 256 + threadIdx.x;  // < B*S*2D
  int e = idx & (2 * DD - 1);
  int bs = idx >> 10;
  int b = bs >> 7;
  float v = (e < DD) ? sr[(size_t)bs * DD + e] : si[(size_t)bs * DD + e - DD];
  out[idx] = acc[idx] + rem[b] * v;
}

extern "C" void kernel_launch(void* const* d_in, const int* in_sizes, int n_in,
                              void* d_out, int out_size, void* d_ws, size_t ws_size,
                              hipStream_t stream) {
  const float* xr = (const float*)d_in[0];
  const float* xi = (const float*)d_in[1];
  const float* Wl_r = (const float*)d_in[2];
  const float* Wl_i = (const float*)d_in[3];
  const float* Wq_r = (const float*)d_in[4];
  const float* Wq_i = (const float*)d_in[5];
  const float* Wk_r = (const float*)d_in[6];
  const float* Wk_i = (const float*)d_in[7];
  const float* Wv_r = (const float*)d_in[8];
  const float* Wv_i = (const float*)d_in[9];
  const float* ln_scale = (const float*)d_in[10];
  const float* ln_shift = (const float*)d_in[11];
  const float* mod_bias = (const float*)d_in[12];
  const float* gate_mask = (const float*)d_in[13];
  const float* score_w = (const float*)d_in[14];
  const float* score_b = (const float*)d_in[15];
  const float* conf_w = (const float*)d_in[16];
  const float* conf_b = (const float*)d_in[17];
  const float* halt_w = (const float*)d_in[18];
  const float* halt_b = (const float*)d_in[19];
  const float* ctrl_w = (const float*)d_in[20];
  const float* ctrl_b = (const float*)d_in[21];
  const float* st_score_w = (const float*)d_in[22];
  const float* st_score_b = (const float*)d_in[23];
  const float* st_conf_w = (const float*)d_in[24];
  const float* st_conf_b = (const float*)d_in[25];
  float* out = (float*)d_out;

  const int BSD = BB * SS * DD;        // 262144
  const size_t WSLOT = (size_t)MM * DD * 1024;  // u16 per weight matrix

  char* pc = (char*)d_ws;
  float* sr = (float*)pc; pc += (size_t)BSD * 4;
  float* si = (float*)pc; pc += (size_t)BSD * 4;
  float* zr = (float*)pc; pc += (size_t)2 * BMSD * 4;   // 2 split-K partials
  float* zi = (float*)pc; pc += (size_t)2 * BMSD * 4;
  float* prb = (float*)pc; pc += (size_t)BMSD * 4;
  float* pib = (float*)pc; pc += (size_t)BMSD * 4;
  float* scorev = (float*)pc; pc += (size_t)BB * MM * SS * 4;
  float* confv = (float*)pc; pc += (size_t)BB * MM * SS * 4;
  float* haltv = (float*)pc; pc += (size_t)BB * MM * SS * 4;
  float* flat = (float*)pc; pc += (size_t)BB * 2 * DD * 4;
  float* memv = (float*)pc; pc += (size_t)BB * KK * 2 * DD * 4;
  float* ptrv = (float*)pc; pc += (size_t)BB * KK * 4;
  float* readv = (float*)pc; pc += (size_t)BB * 2 * DD * 4;
  float* stv = (float*)pc; pc += (size_t)2 * BB * 4;
  float* accb = (float*)pc; pc += (size_t)BB * SS * 2 * DD * 4;
  float* rem2 = (float*)pc; pc += (size_t)2 * BB * 4;   // parity double-buffer
  u16* crbf = (u16*)pc; pc += (size_t)BB * SS * 1024 * 2;
  u16* cibf = (u16*)pc; pc += (size_t)BB * SS * 1024 * 2;
  u16* zbr = (u16*)pc; pc += (size_t)BB * MM * SS * 1024 * 2;
  u16* zbi = (u16*)pc; pc += (size_t)BB * MM * SS * 1024 * 2;
  u16* qbr = (u16*)pc; pc += (size_t)BB * MM * SS * 1024 * 2;  // Y real
  u16* qbi = (u16*)pc; pc += (size_t)BB * MM * SS * 1024 * 2;  // Y imag
  u16* vbr = (u16*)pc; pc += (size_t)BB * MM * SS * 1024 * 2;
  u16* vbi = (u16*)pc; pc += (size_t)BB * MM * SS * 1024 * 2;
  u16* Pb  = (u16*)pc; pc += (size_t)BB * MM * SS * 256 * 2;
  u16* wbf = (u16*)pc; pc += 10 * WSLOT * 2;                   // slots 0,1 Wl; 6,7 Wv; 8,9 H
  u16* wqtr = (u16*)pc; pc += WSLOT * 2;                       // WqT split
  u16* wqti = (u16*)pc; pc += WSLOT * 2;
  u16* wktr = (u16*)pc; pc += WSLOT * 2;                       // WkT split
  u16* wkti = (u16*)pc; pc += WSLOT * 2;
  float* hfr = (float*)pc; pc += (size_t)MM * DD * DD * 4;     // H fp32
  float* hfi = (float*)pc; pc += (size_t)MM * DD * DD * 4;

  // ---- one-time (per launch) weight preprocessing ----
  k_zero<<<(BB * 2 * DD) / 256, 256, 0, stream>>>(flat);
  k_convw<<<4096, 256, 0, stream>>>(Wl_r, wbf + 0 * WSLOT);
  k_convw<<<4096, 256, 0, stream>>>(Wl_i, wbf + 1 * WSLOT);
  k_convw<<<4096, 256, 0, stream>>>(Wv_r, wbf + 6 * WSLOT);
  k_convw<<<4096, 256, 0, stream>>>(Wv_i, wbf + 7 * WSLOT);

  dim3 tgrid(8, 8, 4);
  k_convt<<<tgrid, 256, 0, stream>>>(Wq_r, wqtr);
  k_convt<<<tgrid, 256, 0, stream>>>(Wq_i, wqti);
  k_convt<<<tgrid, 256, 0, stream>>>(Wk_r, wktr);
  k_convt<<<tgrid, 256, 0, stream>>>(Wk_i, wkti);

  // H[e,d] = sum_o conj(WkT[e,o]) * WqT[d,o]
  dim3 hgrid(8, 8, 4);
  k_gemm_g<<<hgrid, 256, 0, stream>>>(wktr, wkti, wqtr, wqti, hfr, hfi);
  k_convw<<<4096, 256, 0, stream>>>(hfr, wbf + 8 * WSLOT);
  k_convw<<<4096, 256, 0, stream>>>(hfi, wbf + 9 * WSLOT);

  k_init<<<2048, 256, 0, stream>>>(xr, xi, sr, si, accb, memv, ptrv, rem2, crbf, cibf, flat);

  dim3 ggrid(DD / 64, (BB * SS) / 64, MM * 2);    // 512 blocks (split-K x2)
  dim3 qgrid(DD / 64, (BB * SS) / 64, MM * 2);    // 512 blocks (Y + V only)
  dim3 smgrid(1, SS / 64, BB * MM);               // 32 blocks
  dim3 pvgrid(DD / 64, SS / 64, BB * MM);         // 256 blocks

  for (int step = 0; step < NSTEPS; ++step) {
    k_stack<<<BB, 512, 0, stream>>>(flat, ctrl_w, ctrl_b, ptrv, memv, readv,
                                    st_score_w, st_conf_w, st_score_b, st_conf_b,
                                    stv, scorev, confv, haltv);
    k_gemm_mfma<<<ggrid, 256, 0, stream>>>(crbf, cibf, wbf + 0 * WSLOT, wbf + 1 * WSLOT, zr, zi);
    k_lnphase<<<BB * MM * SS, 128, 0, stream>>>(zr, zi, ln_scale, ln_shift, mod_bias, zbr, zbi);
    k_gemm_qkv<<<qgrid, 256, 0, stream>>>(zbr, zbi, wbf, WSLOT, qbr, qbi, vbr, vbi);
    k_scores_sm<<<smgrid, 256, 0, stream>>>(qbr, qbi, zbr, zbi, Pb);
    k_pv<<<pvgrid, 256, 0, stream>>>(Pb, vbr, vbi, gate_mask, score_w, conf_w, halt_w,
                                     prb, pib, scorev, confv, haltv);
    k_combine<<<BB * SS, 256, 0, stream>>>(prb, pib, scorev, confv, score_b, conf_b,
                                           haltv, halt_b, stv, readv, rem2, step & 1,
                                           xr, xi, sr, si, accb, crbf, cibf, flat);
  }

  k_final<<<(BB * SS * 2 * DD) / 256, 256, 0, stream>>>(accb, rem2, sr, si, out);
}

// Round 7
// 2120.993 us; speedup vs baseline: 1.0702x; 1.0702x over previous
//
#include <hip/hip_runtime.h>

#define DD 512
#define MM 4
#define BB 4
#define SS 128
#define KK 32
#define NSTEPS 16
#define EPSF 1e-6f
#define SCALEF 0.04419417382415922f  // 512^-0.5
#define BMSD (BB * MM * SS * DD)

typedef unsigned short u16;
typedef __bf16 bf16x8 __attribute__((ext_vector_type(8)));
typedef u16 u16x8 __attribute__((ext_vector_type(8)));
typedef float f32x16 __attribute__((ext_vector_type(16)));
typedef unsigned int u32x4 __attribute__((ext_vector_type(4)));

__device__ inline void split_bf16(float x, u16& h, u16& l) {
  __bf16 hb = (__bf16)x;
  float hf = (float)hb;
  __bf16 lb = (__bf16)(x - hf);
  h = __builtin_bit_cast(u16, hb);
  l = __builtin_bit_cast(u16, lb);
}

// ---------------- weight fp32 -> split bf16 [row][1024] (hi | lo) ----------------
__global__ void k_convw(const float* __restrict__ src, u16* __restrict__ dst) {
  int idx = blockIdx.x * 256 + threadIdx.x;  // over M*D*D
  int row = idx >> 9, k = idx & 511;
  u16 h, l;
  split_bf16(src[idx], h, l);
  dst[(size_t)row * 1024 + k] = h;
  dst[(size_t)row * 1024 + 512 + k] = l;
}

// ---------------- transpose-convert: fp32 [m][o][d] -> split bf16 [m*D+d][o hi|lo] ----------------
__global__ void k_convt(const float* __restrict__ src, u16* __restrict__ dst) {
  __shared__ float tile[64][65];
  int m = blockIdx.z;
  int o0 = blockIdx.y * 64, d0 = blockIdx.x * 64;
  int tid = threadIdx.x;  // 256
  int g = tid >> 6, lane = tid & 63;
#pragma unroll
  for (int i = 0; i < 16; i++) {
    int o_l = g * 16 + i;
    tile[o_l][lane] = src[(size_t)(m * 512 + o0 + o_l) * 512 + d0 + lane];
  }
  __syncthreads();
#pragma unroll
  for (int i = 0; i < 16; i++) {
    int d_l = g * 16 + i;
    float v = tile[lane][d_l];
    u16 h, l;
    split_bf16(v, h, l);
    size_t drow = (size_t)(m * 512 + d0 + d_l) * 1024;
    dst[drow + o0 + lane] = h;
    dst[drow + 512 + o0 + lane] = l;
  }
}

// ---------------- init ----------------
__global__ void k_init(const float* __restrict__ xr, const float* __restrict__ xi,
                       float* __restrict__ sr, float* __restrict__ si,
                       float* __restrict__ acc, float* __restrict__ memv,
                       float* __restrict__ ptrv, float* __restrict__ rem,
                       u16* __restrict__ crbf, u16* __restrict__ cibf) {
  int idx = blockIdx.x * 256 + threadIdx.x;
  if (idx < BB * SS * 2 * DD) acc[idx] = 0.f;
  if (idx < BB * SS * DD) {
    float a = xr[idx], b = xi[idx];
    sr[idx] = a; si[idx] = b;
    int row = idx >> 9, d = idx & 511;
    u16 h, l;
    split_bf16(a, h, l);   // c0 = 0.5x + 0.5x = x
    crbf[(size_t)row * 1024 + d] = h;
    crbf[(size_t)row * 1024 + 512 + d] = l;
    split_bf16(b, h, l);
    cibf[(size_t)row * 1024 + d] = h;
    cibf[(size_t)row * 1024 + 512 + d] = l;
  }
  if (idx < BB * KK * 2 * DD) memv[idx] = 0.f;
  if (idx < BB * KK) ptrv[idx] = ((idx & (KK - 1)) == 0) ? 1.f : 0.f;
  if (idx < BB) rem[idx] = 1.f;
}

// ---------------- flat_in + control softmax + ptr update + head-acc zero ----------------
__global__ void k_flatctrl(const float* __restrict__ sr, const float* __restrict__ si,
                           const float* __restrict__ ctrl_w, const float* __restrict__ ctrl_b,
                           float* __restrict__ ptrv, float* __restrict__ flat_in,
                           float* __restrict__ nptrg, float* __restrict__ wmg,
                           float* __restrict__ stacc,
                           float* __restrict__ scorev, float* __restrict__ confv,
                           float* __restrict__ haltv) {
  int b = blockIdx.x;
  int tid = threadIdx.x;  // 256
  __shared__ float red[3 * 256];
  __shared__ float ctrl[3], optr[KK], nptr_s[KK], wm_s[KK], normf;

  if (tid < KK) optr[tid] = ptrv[b * KK + tid];

  // zero head accumulators for this b (k_pv accumulates raw dots atomically)
#pragma unroll
  for (int i = 0; i < 2; i++) {
    int r = b * MM * SS + tid + i * 256;
    scorev[r] = 0.f; confv[r] = 0.f; haltv[r] = 0.f;
  }

  int e4 = tid * 4;
  const float* basep = (e4 < DD) ? sr : si;
  int d4 = (e4 < DD) ? e4 : (e4 - DD);
  float4 accv = make_float4(0.f, 0.f, 0.f, 0.f);
  size_t base = (size_t)b * SS * DD + d4;
  for (int s = 0; s < SS; s++) {
    float4 v = *(const float4*)&basep[base + (size_t)s * DD];
    accv.x += v.x; accv.y += v.y; accv.z += v.z; accv.w += v.w;
  }
  accv.x *= (1.0f / SS); accv.y *= (1.0f / SS); accv.z *= (1.0f / SS); accv.w *= (1.0f / SS);
  *(float4*)&flat_in[b * 2 * DD + e4] = accv;
  float fv[4] = {accv.x, accv.y, accv.z, accv.w};
  float d0 = 0.f, d1 = 0.f, d2 = 0.f;
#pragma unroll
  for (int j = 0; j < 4; j++) {
    d0 += fv[j] * ctrl_w[(e4 + j) * 3 + 0];
    d1 += fv[j] * ctrl_w[(e4 + j) * 3 + 1];
    d2 += fv[j] * ctrl_w[(e4 + j) * 3 + 2];
  }
  red[tid] = d0; red[256 + tid] = d1; red[512 + tid] = d2;
  __syncthreads();
  for (int off = 128; off > 0; off >>= 1) {
    if (tid < off) {
      red[tid] += red[tid + off];
      red[256 + tid] += red[256 + tid + off];
      red[512 + tid] += red[512 + tid + off];
    }
    __syncthreads();
  }
  if (tid == 0) {
    float l0 = red[0] + ctrl_b[0], l1 = red[256] + ctrl_b[1], l2 = red[512] + ctrl_b[2];
    float mx = fmaxf(l0, fmaxf(l1, l2));
    float e0 = expf(l0 - mx), e1 = expf(l1 - mx), e2 = expf(l2 - mx);
    float s = e0 + e1 + e2;
    ctrl[0] = e0 / s; ctrl[1] = e1 / s; ctrl[2] = e2 / s;
    stacc[b * 2] = 0.f; stacc[b * 2 + 1] = 0.f;
  }
  __syncthreads();
  if (tid < KK) {
    float up = optr[(tid + KK - 1) & (KK - 1)];
    float dn = optr[(tid + 1) & (KK - 1)];
    float cu = optr[tid];
    nptr_s[tid] = ctrl[0] * up + ctrl[1] * dn + ctrl[2] * cu;
    wm_s[tid] = ctrl[0] * up;
  }
  __syncthreads();
  if (tid == 0) {
    float s = 0.f;
    for (int k = 0; k < KK; k++) s += nptr_s[k];
    normf = 1.f / (s + EPSF);
  }
  __syncthreads();
  if (tid < KK) {
    float np = nptr_s[tid] * normf;
    ptrv[b * KK + tid] = np;
    nptrg[b * KK + tid] = np;
    wmg[b * KK + tid] = wm_s[tid];
  }
}

#define LSTR 72  // LDS row stride in bf16 elems

// ---------------- Wl complex NT GEMM, split-K x2 (even/odd chunks), fp32 partials ----------------
__global__ __launch_bounds__(256) void k_gemm_mfma(
    const u16* __restrict__ Ar, const u16* __restrict__ Ai,
    const u16* __restrict__ Wr, const u16* __restrict__ Wi,
    float* __restrict__ Cr, float* __restrict__ Ci) {
  __shared__ u16 sAr[64][LSTR], sAi[64][LSTR], sWr[64][LSTR], sWi[64][LSTR];
  int mz = blockIdx.z;
  int m = mz & (MM - 1), split = mz >> 2;
  int row_blk = blockIdx.y * 64, o_blk = blockIdx.x * 64;
  int tid = threadIdx.x;

  int lrow = tid >> 3, lk8 = (tid & 7) << 3;
  size_t arow0 = (size_t)(row_blk + lrow), arow1 = arow0 + 32;  // dense b*S+s rows
  size_t wrow0 = (size_t)m * DD + o_blk + lrow, wrow1 = wrow0 + 32;

  int wave = tid >> 6, lane = tid & 63;
  int wrow = (wave >> 1) * 32, wcol = (wave & 1) * 32;
  int l31 = lane & 31, khalf = (lane >> 5) * 8;

  f32x16 accP, accN, accI;
  for (int i = 0; i < 16; i++) { accP[i] = 0.f; accN[i] = 0.f; accI[i] = 0.f; }

  int it20 = split;
  int seg0 = it20 >> 3, k00 = (it20 & 7) * 64;
  int aofs0 = (seg0 == 1) ? 512 : 0, wofs0 = (seg0 == 2) ? 512 : 0;
  u16x8 g0 = *(const u16x8*)&Ar[arow0 * 1024 + aofs0 + k00 + lk8];
  u16x8 g1 = *(const u16x8*)&Ar[arow1 * 1024 + aofs0 + k00 + lk8];
  u16x8 g2 = *(const u16x8*)&Ai[arow0 * 1024 + aofs0 + k00 + lk8];
  u16x8 g3 = *(const u16x8*)&Ai[arow1 * 1024 + aofs0 + k00 + lk8];
  u16x8 g4 = *(const u16x8*)&Wr[wrow0 * 1024 + wofs0 + k00 + lk8];
  u16x8 g5 = *(const u16x8*)&Wr[wrow1 * 1024 + wofs0 + k00 + lk8];
  u16x8 g6 = *(const u16x8*)&Wi[wrow0 * 1024 + wofs0 + k00 + lk8];
  u16x8 g7 = *(const u16x8*)&Wi[wrow1 * 1024 + wofs0 + k00 + lk8];

  for (int jt = 0; jt < 12; ++jt) {
    __syncthreads();  // prev iter's LDS reads complete
    *(u16x8*)&sAr[lrow][lk8] = g0;
    *(u16x8*)&sAr[lrow + 32][lk8] = g1;
    *(u16x8*)&sAi[lrow][lk8] = g2;
    *(u16x8*)&sAi[lrow + 32][lk8] = g3;
    *(u16x8*)&sWr[lrow][lk8] = g4;
    *(u16x8*)&sWr[lrow + 32][lk8] = g5;
    *(u16x8*)&sWi[lrow][lk8] = g6;
    *(u16x8*)&sWi[lrow + 32][lk8] = g7;
    u16x8 n0, n1, n2, n3, n4, n5, n6, n7;
    if (jt < 11) {
      int it2 = 2 * (jt + 1) + split, seg = it2 >> 3, k0 = (it2 & 7) * 64;
      int aofs = (seg == 1) ? 512 : 0, wofs = (seg == 2) ? 512 : 0;
      n0 = *(const u16x8*)&Ar[arow0 * 1024 + aofs + k0 + lk8];
      n1 = *(const u16x8*)&Ar[arow1 * 1024 + aofs + k0 + lk8];
      n2 = *(const u16x8*)&Ai[arow0 * 1024 + aofs + k0 + lk8];
      n3 = *(const u16x8*)&Ai[arow1 * 1024 + aofs + k0 + lk8];
      n4 = *(const u16x8*)&Wr[wrow0 * 1024 + wofs + k0 + lk8];
      n5 = *(const u16x8*)&Wr[wrow1 * 1024 + wofs + k0 + lk8];
      n6 = *(const u16x8*)&Wi[wrow0 * 1024 + wofs + k0 + lk8];
      n7 = *(const u16x8*)&Wi[wrow1 * 1024 + wofs + k0 + lk8];
    }
    __syncthreads();
#pragma unroll
    for (int kk = 0; kk < 64; kk += 16) {
      bf16x8 fAr = *(const bf16x8*)&sAr[wrow + l31][kk + khalf];
      bf16x8 fAi = *(const bf16x8*)&sAi[wrow + l31][kk + khalf];
      bf16x8 fWr = *(const bf16x8*)&sWr[wcol + l31][kk + khalf];
      bf16x8 fWi = *(const bf16x8*)&sWi[wcol + l31][kk + khalf];
      accP = __builtin_amdgcn_mfma_f32_32x32x16_bf16(fAr, fWr, accP, 0, 0, 0);
      accN = __builtin_amdgcn_mfma_f32_32x32x16_bf16(fAi, fWi, accN, 0, 0, 0);
      accI = __builtin_amdgcn_mfma_f32_32x32x16_bf16(fAi, fWr, accI, 0, 0, 0);
      accI = __builtin_amdgcn_mfma_f32_32x32x16_bf16(fAr, fWi, accI, 0, 0, 0);
    }
    if (jt < 11) {
      g0 = n0; g1 = n1; g2 = n2; g3 = n3; g4 = n4; g5 = n5; g6 = n6; g7 = n7;
    }
  }

  int o = o_blk + wcol + l31;
  size_t sofs = (size_t)split * BMSD;
#pragma unroll
  for (int reg = 0; reg < 16; reg++) {
    int r_in = (reg & 3) + 8 * (reg >> 2) + 4 * (lane >> 5);
    int gr = row_blk + wrow + r_in;
    int b = gr >> 7, s = gr & (SS - 1);
    size_t crow = (size_t)((b * MM + m) * SS + s);
    Cr[sofs + crow * DD + o] = accP[reg] - accN[reg];
    Ci[sofs + crow * DD + o] = accI[reg];
  }
}

// ---------------- one-time: H[e,d] = sum_o conj(WkT[e,o]) * WqT[d,o]  (fp32 out) ----------------
__global__ __launch_bounds__(256) void k_gemm_g(
    const u16* __restrict__ Ar, const u16* __restrict__ Ai,
    const u16* __restrict__ Wr, const u16* __restrict__ Wi,
    float* __restrict__ Hr, float* __restrict__ Hi) {
  __shared__ u16 sAr[64][LSTR], sAi[64][LSTR], sWr[64][LSTR], sWi[64][LSTR];
  int m = blockIdx.z;
  int row_blk = blockIdx.y * 64, o_blk = blockIdx.x * 64;
  int tid = threadIdx.x;

  int lrow = tid >> 3, lk8 = (tid & 7) << 3;
  size_t arow0 = (size_t)(m * 512 + row_blk + lrow), arow1 = arow0 + 32;
  size_t wrow0 = (size_t)(m * 512 + o_blk + lrow), wrow1 = wrow0 + 32;

  int wave = tid >> 6, lane = tid & 63;
  int wrow = (wave >> 1) * 32, wcol = (wave & 1) * 32;
  int l31 = lane & 31, khalf = (lane >> 5) * 8;

  f32x16 accP, accN, accI;
  for (int i = 0; i < 16; i++) { accP[i] = 0.f; accN[i] = 0.f; accI[i] = 0.f; }

  u16x8 g0 = *(const u16x8*)&Ar[arow0 * 1024 + lk8];
  u16x8 g1 = *(const u16x8*)&Ar[arow1 * 1024 + lk8];
  u16x8 g2 = *(const u16x8*)&Ai[arow0 * 1024 + lk8];
  u16x8 g3 = *(const u16x8*)&Ai[arow1 * 1024 + lk8];
  u16x8 g4 = *(const u16x8*)&Wr[wrow0 * 1024 + lk8];
  u16x8 g5 = *(const u16x8*)&Wr[wrow1 * 1024 + lk8];
  u16x8 g6 = *(const u16x8*)&Wi[wrow0 * 1024 + lk8];
  u16x8 g7 = *(const u16x8*)&Wi[wrow1 * 1024 + lk8];

  for (int it = 0; it < 24; ++it) {
    __syncthreads();
    *(u16x8*)&sAr[lrow][lk8] = g0;
    *(u16x8*)&sAr[lrow + 32][lk8] = g1;
    *(u16x8*)&sAi[lrow][lk8] = g2;
    *(u16x8*)&sAi[lrow + 32][lk8] = g3;
    *(u16x8*)&sWr[lrow][lk8] = g4;
    *(u16x8*)&sWr[lrow + 32][lk8] = g5;
    *(u16x8*)&sWi[lrow][lk8] = g6;
    *(u16x8*)&sWi[lrow + 32][lk8] = g7;
    u16x8 n0, n1, n2, n3, n4, n5, n6, n7;
    if (it < 23) {
      int it2 = it + 1, seg = it2 >> 3, k0 = (it2 & 7) * 64;
      int aofs = (seg == 1) ? 512 : 0, wofs = (seg == 2) ? 512 : 0;
      n0 = *(const u16x8*)&Ar[arow0 * 1024 + aofs + k0 + lk8];
      n1 = *(const u16x8*)&Ar[arow1 * 1024 + aofs + k0 + lk8];
      n2 = *(const u16x8*)&Ai[arow0 * 1024 + aofs + k0 + lk8];
      n3 = *(const u16x8*)&Ai[arow1 * 1024 + aofs + k0 + lk8];
      n4 = *(const u16x8*)&Wr[wrow0 * 1024 + wofs + k0 + lk8];
      n5 = *(const u16x8*)&Wr[wrow1 * 1024 + wofs + k0 + lk8];
      n6 = *(const u16x8*)&Wi[wrow0 * 1024 + wofs + k0 + lk8];
      n7 = *(const u16x8*)&Wi[wrow1 * 1024 + wofs + k0 + lk8];
    }
    __syncthreads();
#pragma unroll
    for (int kk = 0; kk < 64; kk += 16) {
      bf16x8 fAr = *(const bf16x8*)&sAr[wrow + l31][kk + khalf];
      bf16x8 fAi = *(const bf16x8*)&sAi[wrow + l31][kk + khalf];
      bf16x8 fWr = *(const bf16x8*)&sWr[wcol + l31][kk + khalf];
      bf16x8 fWi = *(const bf16x8*)&sWi[wcol + l31][kk + khalf];
      u32x4 t = __builtin_bit_cast(u32x4, fAi) ^ 0x80008000u;
      bf16x8 nAi = __builtin_bit_cast(bf16x8, t);
      accP = __builtin_amdgcn_mfma_f32_32x32x16_bf16(fAr, fWr, accP, 0, 0, 0);
      accN = __builtin_amdgcn_mfma_f32_32x32x16_bf16(fAi, fWi, accN, 0, 0, 0);
      accI = __builtin_amdgcn_mfma_f32_32x32x16_bf16(fAr, fWi, accI, 0, 0, 0);
      accI = __builtin_amdgcn_mfma_f32_32x32x16_bf16(nAi, fWr, accI, 0, 0, 0);
    }
    if (it < 23) {
      g0 = n0; g1 = n1; g2 = n2; g3 = n3; g4 = n4; g5 = n5; g6 = n6; g7 = n7;
    }
  }

  int o = o_blk + wcol + l31;
#pragma unroll
  for (int reg = 0; reg < 16; reg++) {
    int r_in = (reg & 3) + 8 * (reg >> 2) + 4 * (lane >> 5);
    int gr = row_blk + wrow + r_in;          // e in [0,512)
    size_t crow = (size_t)(m * 512 + gr);
    Hr[crow * DD + o] = accP[reg] + accN[reg];
    Hi[crow * DD + o] = accI[reg];
  }
}

// ---------------- merged Y/V GEMM (K GEMM eliminated via H folding) ----------------
// Grid reordered: blockIdx.x = (m,w) combo so XCD = combo -> per-XCD working set
// = A m-slice (2MB) + one weight matrix m-slice (2MB) = 4MB = L2 size.
__global__ __launch_bounds__(256) void k_gemm_qkv(
    const u16* __restrict__ Ar, const u16* __restrict__ Ai,
    const u16* __restrict__ wbf, size_t WSLOT,
    u16* __restrict__ qbr, u16* __restrict__ qbi,
    u16* __restrict__ vbr, u16* __restrict__ vbi) {
  __shared__ u16 sAr[64][LSTR], sAi[64][LSTR], sWr[64][LSTR], sWi[64][LSTR];
  int zid = blockIdx.x;                          // fastest dim -> XCD = combo
  int m = zid >> 1, w = zid & 1;                 // w=0: Y (H slot 8), w=1: V (Wv slot 6)
  int slot = (w == 0) ? 8 : 6;
  const u16* Wr = wbf + (size_t)slot * WSLOT;
  const u16* Wi = Wr + WSLOT;
  int row_blk = blockIdx.z * 64, o_blk = blockIdx.y * 64;
  int tid = threadIdx.x;

  int lrow = tid >> 3, lk8 = (tid & 7) << 3;
  int gr0 = row_blk + lrow, gr1 = gr0 + 32;
  size_t arow0 = (size_t)(((gr0 >> 7) * MM + m) * SS + (gr0 & (SS - 1)));
  size_t arow1 = (size_t)(((gr1 >> 7) * MM + m) * SS + (gr1 & (SS - 1)));
  size_t wrow0 = (size_t)m * DD + o_blk + lrow, wrow1 = wrow0 + 32;

  int wave = tid >> 6, lane = tid & 63;
  int wrow = (wave >> 1) * 32, wcol = (wave & 1) * 32;
  int l31 = lane & 31, khalf = (lane >> 5) * 8;

  f32x16 accP, accN, accI;
  for (int i = 0; i < 16; i++) { accP[i] = 0.f; accN[i] = 0.f; accI[i] = 0.f; }

  u16x8 g0 = *(const u16x8*)&Ar[arow0 * 1024 + lk8];
  u16x8 g1 = *(const u16x8*)&Ar[arow1 * 1024 + lk8];
  u16x8 g2 = *(const u16x8*)&Ai[arow0 * 1024 + lk8];
  u16x8 g3 = *(const u16x8*)&Ai[arow1 * 1024 + lk8];
  u16x8 g4 = *(const u16x8*)&Wr[wrow0 * 1024 + lk8];
  u16x8 g5 = *(const u16x8*)&Wr[wrow1 * 1024 + lk8];
  u16x8 g6 = *(const u16x8*)&Wi[wrow0 * 1024 + lk8];
  u16x8 g7 = *(const u16x8*)&Wi[wrow1 * 1024 + lk8];

  for (int it = 0; it < 24; ++it) {
    __syncthreads();
    *(u16x8*)&sAr[lrow][lk8] = g0;
    *(u16x8*)&sAr[lrow + 32][lk8] = g1;
    *(u16x8*)&sAi[lrow][lk8] = g2;
    *(u16x8*)&sAi[lrow + 32][lk8] = g3;
    *(u16x8*)&sWr[lrow][lk8] = g4;
    *(u16x8*)&sWr[lrow + 32][lk8] = g5;
    *(u16x8*)&sWi[lrow][lk8] = g6;
    *(u16x8*)&sWi[lrow + 32][lk8] = g7;
    u16x8 n0, n1, n2, n3, n4, n5, n6, n7;
    if (it < 23) {
      int it2 = it + 1, seg = it2 >> 3, k0 = (it2 & 7) * 64;
      int aofs = (seg == 1) ? 512 : 0, wofs = (seg == 2) ? 512 : 0;
      n0 = *(const u16x8*)&Ar[arow0 * 1024 + aofs + k0 + lk8];
      n1 = *(const u16x8*)&Ar[arow1 * 1024 + aofs + k0 + lk8];
      n2 = *(const u16x8*)&Ai[arow0 * 1024 + aofs + k0 + lk8];
      n3 = *(const u16x8*)&Ai[arow1 * 1024 + aofs + k0 + lk8];
      n4 = *(const u16x8*)&Wr[wrow0 * 1024 + wofs + k0 + lk8];
      n5 = *(const u16x8*)&Wr[wrow1 * 1024 + wofs + k0 + lk8];
      n6 = *(const u16x8*)&Wi[wrow0 * 1024 + wofs + k0 + lk8];
      n7 = *(const u16x8*)&Wi[wrow1 * 1024 + wofs + k0 + lk8];
    }
    __syncthreads();
#pragma unroll
    for (int kk = 0; kk < 64; kk += 16) {
      bf16x8 fAr = *(const bf16x8*)&sAr[wrow + l31][kk + khalf];
      bf16x8 fAi = *(const bf16x8*)&sAi[wrow + l31][kk + khalf];
      bf16x8 fWr = *(const bf16x8*)&sWr[wcol + l31][kk + khalf];
      bf16x8 fWi = *(const bf16x8*)&sWi[wcol + l31][kk + khalf];
      accP = __builtin_amdgcn_mfma_f32_32x32x16_bf16(fAr, fWr, accP, 0, 0, 0);
      accN = __builtin_amdgcn_mfma_f32_32x32x16_bf16(fAi, fWi, accN, 0, 0, 0);
      accI = __builtin_amdgcn_mfma_f32_32x32x16_bf16(fAi, fWr, accI, 0, 0, 0);
      accI = __builtin_amdgcn_mfma_f32_32x32x16_bf16(fAr, fWi, accI, 0, 0, 0);
    }
    if (it < 23) {
      g0 = n0; g1 = n1; g2 = n2; g3 = n3; g4 = n4; g5 = n5; g6 = n6; g7 = n7;
    }
  }

  u16* Cr = (w == 0) ? qbr : vbr;
  u16* Ci = (w == 0) ? qbi : vbi;
  int o = o_blk + wcol + l31;
#pragma unroll
  for (int reg = 0; reg < 16; reg++) {
    int r_in = (reg & 3) + 8 * (reg >> 2) + 4 * (lane >> 5);
    int gr = row_blk + wrow + r_in;
    int b = gr >> 7, s = gr & (SS - 1);
    size_t crow = (size_t)((b * MM + m) * SS + s);
    u16 h, l;
    split_bf16(accP[reg] - accN[reg], h, l);
    Cr[crow * 1024 + o] = h;
    Cr[crow * 1024 + 512 + o] = l;
    split_bf16(accI[reg], h, l);
    Ci[crow * 1024 + o] = h;
    Ci[crow * 1024 + 512 + o] = l;
  }
}

// ---------------- scores + fused softmax -> split P (reg-prefetch pipelined) ----------------
// Q inputs = Y buffers; K inputs = z buffers (H-folded attention).
__global__ __launch_bounds__(256) void k_scores_sm(
    const u16* __restrict__ Q_r, const u16* __restrict__ Q_i,
    const u16* __restrict__ K_r, const u16* __restrict__ K_i,
    u16* __restrict__ Pb) {
  __shared__ __align__(16) char smem[55296];  // 54 KB
  u16 (*sQr)[LSTR] = (u16(*)[LSTR])smem;                  // 64 rows
  u16 (*sQi)[LSTR] = (u16(*)[LSTR])(smem + 9216);         // 64 rows
  u16 (*sKr)[LSTR] = (u16(*)[LSTR])(smem + 18432);        // 128 rows
  u16 (*sKi)[LSTR] = (u16(*)[LSTR])(smem + 36864);        // 128 rows
  float (*stile)[132] = (float(*)[132])smem;              // 64 x 132 overlay (33792 B)

  int bm = blockIdx.z;
  int s_blk = blockIdx.y * 64;
  int tid = threadIdx.x;
  int lrow = tid >> 3, lk8 = (tid & 7) << 3;
  size_t qrow0 = (size_t)(bm * SS + s_blk + lrow), qrow1 = qrow0 + 32;
  size_t krow = (size_t)(bm * SS + lrow);  // +0,32,64,96

  int wave = tid >> 6, lane = tid & 63;
  int srow_w = (wave & 1) * 32;
  int tcol_w = (wave >> 1) * 64;
  int l31 = lane & 31, khalf = (lane >> 5) * 8;

  f32x16 acc0, acc1;
  for (int i = 0; i < 16; i++) { acc0[i] = 0.f; acc1[i] = 0.f; }

  // prologue loads (it=0)
  u16x8 pf[12];
  pf[0] = *(const u16x8*)&Q_r[qrow0 * 1024 + lk8];
  pf[1] = *(const u16x8*)&Q_r[qrow1 * 1024 + lk8];
  pf[2] = *(const u16x8*)&Q_i[qrow0 * 1024 + lk8];
  pf[3] = *(const u16x8*)&Q_i[qrow1 * 1024 + lk8];
#pragma unroll
  for (int q = 0; q < 4; q++) {
    pf[4 + q] = *(const u16x8*)&K_r[(krow + q * 32) * 1024 + lk8];
    pf[8 + q] = *(const u16x8*)&K_i[(krow + q * 32) * 1024 + lk8];
  }

  for (int it = 0; it < 24; ++it) {
    __syncthreads();  // prev iter's LDS reads complete
    *(u16x8*)&sQr[lrow][lk8] = pf[0];
    *(u16x8*)&sQr[lrow + 32][lk8] = pf[1];
    *(u16x8*)&sQi[lrow][lk8] = pf[2];
    *(u16x8*)&sQi[lrow + 32][lk8] = pf[3];
#pragma unroll
    for (int q = 0; q < 4; q++) {
      *(u16x8*)&sKr[lrow + q * 32][lk8] = pf[4 + q];
      *(u16x8*)&sKi[lrow + q * 32][lk8] = pf[8 + q];
    }
    // issue next iter's loads BEFORE compute
    u16x8 nf[12];
    if (it < 23) {
      int it2 = it + 1, seg = it2 >> 3, k0 = (it2 & 7) * 64;
      int qofs = (seg == 1) ? 512 : 0;
      int kofs = (seg == 2) ? 512 : 0;
      nf[0] = *(const u16x8*)&Q_r[qrow0 * 1024 + qofs + k0 + lk8];
      nf[1] = *(const u16x8*)&Q_r[qrow1 * 1024 + qofs + k0 + lk8];
      nf[2] = *(const u16x8*)&Q_i[qrow0 * 1024 + qofs + k0 + lk8];
      nf[3] = *(const u16x8*)&Q_i[qrow1 * 1024 + qofs + k0 + lk8];
#pragma unroll
      for (int q = 0; q < 4; q++) {
        nf[4 + q] = *(const u16x8*)&K_r[(krow + q * 32) * 1024 + kofs + k0 + lk8];
        nf[8 + q] = *(const u16x8*)&K_i[(krow + q * 32) * 1024 + kofs + k0 + lk8];
      }
    }
    __syncthreads();
#pragma unroll
    for (int kk = 0; kk < 64; kk += 16) {
      bf16x8 fQr = *(const bf16x8*)&sQr[srow_w + l31][kk + khalf];
      bf16x8 fQi = *(const bf16x8*)&sQi[srow_w + l31][kk + khalf];
      bf16x8 fKr0 = *(const bf16x8*)&sKr[tcol_w + l31][kk + khalf];
      bf16x8 fKr1 = *(const bf16x8*)&sKr[tcol_w + 32 + l31][kk + khalf];
      bf16x8 fKi0 = *(const bf16x8*)&sKi[tcol_w + l31][kk + khalf];
      bf16x8 fKi1 = *(const bf16x8*)&sKi[tcol_w + 32 + l31][kk + khalf];
      acc0 = __builtin_amdgcn_mfma_f32_32x32x16_bf16(fQr, fKr0, acc0, 0, 0, 0);
      acc0 = __builtin_amdgcn_mfma_f32_32x32x16_bf16(fQi, fKi0, acc0, 0, 0, 0);
      acc1 = __builtin_amdgcn_mfma_f32_32x32x16_bf16(fQr, fKr1, acc1, 0, 0, 0);
      acc1 = __builtin_amdgcn_mfma_f32_32x32x16_bf16(fQi, fKi1, acc1, 0, 0, 0);
    }
    if (it < 23) {
#pragma unroll
      for (int j = 0; j < 12; j++) pf[j] = nf[j];
    }
  }

  // ---- fused softmax over full 128-col rows ----
  __syncthreads();  // staging tiles dead; overlay stile
#pragma unroll
  for (int reg = 0; reg < 16; reg++) {
    int r = srow_w + (reg & 3) + 8 * (reg >> 2) + 4 * (lane >> 5);
    stile[r][tcol_w + l31] = acc0[reg] * SCALEF;
    stile[r][tcol_w + 32 + l31] = acc1[reg] * SCALEF;
  }
  __syncthreads();
  int row = tid >> 2;          // 0..63
  int quarter = tid & 3;       // cols quarter*32..+31
  float mx = -3.4e38f;
#pragma unroll
  for (int j = 0; j < 32; j++) mx = fmaxf(mx, stile[row][quarter * 32 + j]);
  mx = fmaxf(mx, __shfl_xor(mx, 1));
  mx = fmaxf(mx, __shfl_xor(mx, 2));
  float ev[32];
  float sum = 0.f;
#pragma unroll
  for (int j = 0; j < 32; j++) {
    ev[j] = expf(stile[row][quarter * 32 + j] - mx);
    sum += ev[j];
  }
  sum += __shfl_xor(sum, 1);
  sum += __shfl_xor(sum, 2);
  float inv = 1.f / sum;
  size_t prow = (size_t)(bm * SS + s_blk + row) * 256;
#pragma unroll
  for (int j = 0; j < 32; j++) {
    int c = quarter * 32 + j;
    u16 h, l;
    split_bf16(ev[j] * inv, h, l);
    Pb[prow + c] = h;
    Pb[prow + 128 + c] = l;
  }
}

// ---------------- P x V MFMA + gate -> pr/pi fp32, FUSED score/conf/halt head dots ----------------
__global__ __launch_bounds__(256) void k_pv(
    const u16* __restrict__ Pb, const u16* __restrict__ vbr, const u16* __restrict__ vbi,
    const float* __restrict__ gate_mask,
    const float* __restrict__ score_w, const float* __restrict__ conf_w,
    const float* __restrict__ halt_w,
    float* __restrict__ pr, float* __restrict__ pi,
    float* __restrict__ scorev, float* __restrict__ confv, float* __restrict__ haltv) {
  __shared__ u16 sP[64][LSTR], sVr[64][LSTR], sVi[64][LSTR];
  int bm = blockIdx.z;
  int m = bm & (MM - 1);
  int s_blk = blockIdx.y * 64;
  int o_blk = blockIdx.x * 64;
  int tid = threadIdx.x;
  int lrow = tid >> 3, lk8 = (tid & 7) << 3;
  size_t prow0 = (size_t)(bm * SS + s_blk + lrow), prow1 = prow0 + 32;

  int wave = tid >> 6, lane = tid & 63;
  int wrow = (wave >> 1) * 32;   // s
  int wcol = (wave & 1) * 32;    // d
  int l31 = lane & 31, khalf = (lane >> 5) * 8;

  f32x16 accR, accI;
  for (int i = 0; i < 16; i++) { accR[i] = 0.f; accI[i] = 0.f; }

  for (int it = 0; it < 6; ++it) {
    int seg = it >> 1, k0 = (it & 1) * 64;        // t-chunk
    int pofs = (seg == 1) ? 128 : 0;              // P lo half for seg1
    int vofs = (seg == 2) ? 512 : 0;              // V lo half for seg2
    u16x8 p0 = *(const u16x8*)&Pb[prow0 * 256 + pofs + k0 + lk8];
    u16x8 p1 = *(const u16x8*)&Pb[prow1 * 256 + pofs + k0 + lk8];
    size_t vrow0 = (size_t)(bm * SS + k0 + lrow), vrow1 = vrow0 + 32;
    u16x8 v0 = *(const u16x8*)&vbr[vrow0 * 1024 + vofs + o_blk + lk8];
    u16x8 v1 = *(const u16x8*)&vbr[vrow1 * 1024 + vofs + o_blk + lk8];
    u16x8 w0 = *(const u16x8*)&vbi[vrow0 * 1024 + vofs + o_blk + lk8];
    u16x8 w1 = *(const u16x8*)&vbi[vrow1 * 1024 + vofs + o_blk + lk8];
    __syncthreads();
    *(u16x8*)&sP[lrow][lk8] = p0;
    *(u16x8*)&sP[lrow + 32][lk8] = p1;
    *(u16x8*)&sVr[lrow][lk8] = v0;
    *(u16x8*)&sVr[lrow + 32][lk8] = v1;
    *(u16x8*)&sVi[lrow][lk8] = w0;
    *(u16x8*)&sVi[lrow + 32][lk8] = w1;
    __syncthreads();
#pragma unroll
    for (int kk = 0; kk < 64; kk += 16) {
      bf16x8 fP = *(const bf16x8*)&sP[wrow + l31][kk + khalf];
      u16x8 ar, ai;
#pragma unroll
      for (int j = 0; j < 8; j++) {
        ar[j] = sVr[kk + khalf + j][wcol + l31];  // transpose-on-read
        ai[j] = sVi[kk + khalf + j][wcol + l31];
      }
      accR = __builtin_amdgcn_mfma_f32_32x32x16_bf16(fP, __builtin_bit_cast(bf16x8, ar), accR, 0, 0, 0);
      accI = __builtin_amdgcn_mfma_f32_32x32x16_bf16(fP, __builtin_bit_cast(bf16x8, ai), accI, 0, 0, 0);
    }
  }

  int d = o_blk + wcol + l31;
  float g = 1.f / (1.f + expf(-gate_mask[m * DD + d]));
  // head weight slices for this (m, d)
  float swr = score_w[m * 2 * DD + d], swi = score_w[m * 2 * DD + DD + d];
  float cwr = conf_w[m * 2 * DD + d],  cwi = conf_w[m * 2 * DD + DD + d];
  float hwr = halt_w[m * 2 * DD + d],  hwi = halt_w[m * 2 * DD + DD + d];
#pragma unroll
  for (int reg = 0; reg < 16; reg++) {
    int r_in = (reg & 3) + 8 * (reg >> 2) + 4 * (lane >> 5);
    size_t crow = (size_t)(bm * SS + s_blk + wrow + r_in);
    float vR = accR[reg] * g, vI = accI[reg] * g;
    pr[crow * DD + d] = vR;
    pi[crow * DD + d] = vI;
    // per-row head dot partials over this wave's 32 d-lanes
    float ps = vR * swr + vI * swi;
    float pc = vR * cwr + vI * cwi;
    float ph = vR * hwr + vI * hwi;
#pragma unroll
    for (int off = 1; off < 32; off <<= 1) {
      ps += __shfl_xor(ps, off);
      pc += __shfl_xor(pc, off);
      ph += __shfl_xor(ph, off);
    }
    if (l31 == 0) {
      atomicAdd(&scorev[crow], ps);
      atomicAdd(&confv[crow], pc);
      atomicAdd(&haltv[crow], ph);
    }
  }
}

// ---------------- magnitude LN + phase renorm + mod scale -> split bf16 ----------------
// zr/zi carry TWO split-K partials at stride BMSD; summed here.
__global__ void k_lnphase(const float* __restrict__ zr, const float* __restrict__ zi,
                          const float* __restrict__ ln_scale, const float* __restrict__ ln_shift,
                          const float* __restrict__ mod_bias,
                          u16* __restrict__ zbr, u16* __restrict__ zbi) {
  int row = blockIdx.x;            // (b*M+m)*S + s
  int m = (row >> 7) & (MM - 1);
  int tid = threadIdx.x;           // 128
  size_t base = (size_t)row * DD;
  float zrv[4], ziv[4], rv[4];
  float sum = 0.f, sumsq = 0.f;
#pragma unroll
  for (int i = 0; i < 4; i++) {
    int o = tid + i * 128;
    float a = zr[base + o] + zr[(size_t)BMSD + base + o];
    float bv = zi[base + o] + zi[(size_t)BMSD + base + o];
    zrv[i] = a; ziv[i] = bv;
    float r = sqrtf(a * a + bv * bv);
    rv[i] = r;
    float mg = r + EPSF;
    sum += mg;
    sumsq += mg * mg;
  }
  __shared__ float rs[128], rq[128];
  rs[tid] = sum; rq[tid] = sumsq;
  __syncthreads();
  for (int off = 64; off > 0; off >>= 1) {
    if (tid < off) { rs[tid] += rs[tid + off]; rq[tid] += rq[tid + off]; }
    __syncthreads();
  }
  float mean = rs[0] * (1.0f / DD);
  float var = (rq[0] - (float)DD * mean * mean) * (1.0f / (DD - 1));
  float inv = 1.0f / sqrtf(var + EPSF);
#pragma unroll
  for (int i = 0; i < 4; i++) {
    int o = tid + i * 128;
    float mg = rv[i] + EPSF;
    float nm = (mg - mean) * inv * ln_scale[m * DD + o] + ln_shift[m * DD + o];
    float r = rv[i];
    float cosp, sinp;
    if (r > 0.f) { cosp = zrv[i] / r; sinp = ziv[i] / r; }
    else { cosp = 1.f; sinp = 0.f; }
    float z1r = nm * cosp, z1i = nm * sinp;
    float nrm = sqrtf(z1r * z1r + z1i * z1i) + EPSF;
    float sc = fmaxf(nrm + mod_bias[m * DD + o], 0.f) / nrm;
    u16 h, l;
    split_bf16(z1r * sc, h, l);
    zbr[(size_t)row * 1024 + o] = h;
    zbr[(size_t)row * 1024 + 512 + o] = l;
    split_bf16(z1i * sc, h, l);
    zbi[(size_t)row * 1024 + o] = h;
    zbi[(size_t)row * 1024 + 512 + o] = l;
  }
}

// ---------------- stack mem update + read + st dot partials ----------------
__global__ void k_memup(const float* __restrict__ flat_in,
                        const float* __restrict__ nptrg, const float* __restrict__ wmg,
                        float* __restrict__ memv, float* __restrict__ readv,
                        const float* __restrict__ st_score_w, const float* __restrict__ st_conf_w,
                        float* __restrict__ stacc) {
  int b = blockIdx.x >> 2;
  int chunk = blockIdx.x & 3;
  int tid = threadIdx.x;           // 256
  int e = chunk * 256 + tid;       // 0..1023
  __shared__ float nptr[KK], wm[KK];
  __shared__ float red[256], red2[256];
  if (tid < KK) { nptr[tid] = nptrg[b * KK + tid]; wm[tid] = wmg[b * KK + tid]; }
  __syncthreads();
  float fl = flat_in[b * 2 * DD + e];
  float racc = 0.f;
#pragma unroll
  for (int k = 0; k < KK; k++) {
    size_t idx = ((size_t)(b * KK + k)) * 2 * DD + e;
    float nm = wm[k] * fl + memv[idx] * (1.f - wm[k]);
    memv[idx] = nm;
    racc += nm * nptr[k];
  }
  readv[b * 2 * DD + e] = racc;
  red[tid] = racc * st_score_w[e];
  red2[tid] = racc * st_conf_w[e];
  __syncthreads();
  for (int off = 128; off > 0; off >>= 1) {
    if (tid < off) { red[tid] += red[tid + off]; red2[tid] += red2[tid + off]; }
    __syncthreads();
  }
  if (tid == 0) {
    atomicAdd(&stacc[b * 2], red[0]);
    atomicAdd(&stacc[b * 2 + 1], red2[0]);
  }
}

// ---------------- halt p + stv finalize (halt bias applied here; haltv is raw dot) ----------------
__global__ void k_haltp(const float* __restrict__ halt, const float* __restrict__ halt_b,
                        float* __restrict__ rem,
                        float* __restrict__ coeff, const float* __restrict__ stacc,
                        const float* __restrict__ st_score_b, const float* __restrict__ st_conf_b,
                        float* __restrict__ stv) {
  int b = blockIdx.x;
  int tid = threadIdx.x;  // 256
  __shared__ float red[256];
  float v0 = halt[b * MM * SS + tid] + halt_b[tid >> 7];
  float v1 = halt[b * MM * SS + 256 + tid] + halt_b[(tid + 256) >> 7];
  red[tid] = 1.f / (1.f + expf(-v0)) + 1.f / (1.f + expf(-v1));
  __syncthreads();
  for (int off = 128; off > 0; off >>= 1) {
    if (tid < off) red[tid] += red[tid + off];
    __syncthreads();
  }
  if (tid == 0) {
    float p = red[0] * (1.0f / (MM * SS));
    float r = rem[b];
    coeff[b] = p * r;
    rem[b] = r * (1.f - p);
    stv[b] = stacc[b * 2] + st_score_b[0];
    stv[BB + b] = 1.f / (1.f + expf(-(stacc[b * 2 + 1] + st_conf_b[0])));
  }
}

// ---------------- module-mix softmax + new state + acc + next-step c ----------------
// score/conf inputs are raw dots; biases + sigmoid applied here.
__global__ void k_combine(const float* __restrict__ pr, const float* __restrict__ pi,
                          const float* __restrict__ score, const float* __restrict__ conf,
                          const float* __restrict__ score_b, const float* __restrict__ conf_b,
                          const float* __restrict__ stv, const float* __restrict__ readv,
                          const float* __restrict__ coeff,
                          const float* __restrict__ xr, const float* __restrict__ xi,
                          float* __restrict__ sr, float* __restrict__ si, float* __restrict__ acc,
                          u16* __restrict__ crbf, u16* __restrict__ cibf) {
  int bs = blockIdx.x;             // b*S + s
  int b = bs >> 7, s = bs & (SS - 1);
  int tid = threadIdx.x;           // 256
  __shared__ float w[5];
  if (tid == 0) {
    float l[5];
    for (int m = 0; m < MM; m++) {
      int r = (b * MM + m) * SS + s;
      float sc = score[r] + score_b[m];
      float cf = 1.f / (1.f + expf(-(conf[r] + conf_b[m])));
      l[m] = sc * cf;
    }
    l[4] = stv[b] * stv[BB + b];
    float mx = l[0];
    for (int j = 1; j < 5; j++) mx = fmaxf(mx, l[j]);
    float sum = 0.f;
    for (int j = 0; j < 5; j++) { l[j] = expf(l[j] - mx); sum += l[j]; }
    for (int j = 0; j < 5; j++) w[j] = l[j] / sum;
  }
  __syncthreads();
  float cf = coeff[b];
#pragma unroll
  for (int i = 0; i < 2; i++) {
    int d = tid + i * 256;
    float nsr = w[4] * readv[b * 2 * DD + d];
    float nsi = w[4] * readv[b * 2 * DD + DD + d];
#pragma unroll
    for (int m = 0; m < MM; m++) {
      size_t off = ((size_t)((b * MM + m) * SS + s)) * DD + d;
      nsr += w[m] * pr[off];
      nsi += w[m] * pi[off];
    }
    size_t sidx = (size_t)bs * DD + d;
    sr[sidx] = nsr;
    si[sidx] = nsi;
    size_t aoff = (size_t)bs * 2 * DD;
    acc[aoff + d] += cf * nsr;
    acc[aoff + DD + d] += cf * nsi;
    u16 h, l;
    split_bf16(0.5f * xr[sidx] + 0.5f * nsr, h, l);
    crbf[(size_t)bs * 1024 + d] = h;
    crbf[(size_t)bs * 1024 + 512 + d] = l;
    split_bf16(0.5f * xi[sidx] + 0.5f * nsi, h, l);
    cibf[(size_t)bs * 1024 + d] = h;
    cibf[(size_t)bs * 1024 + 512 + d] = l;
  }
}

// ---------------- out = acc + rem * concat(sr, si) ----------------
__global__ void k_final(const float* __restrict__ acc, const float* __restrict__ rem,
                        const float* __restrict__ sr, const float* __restrict__ si,
                        float* __restrict__ out) {
  int idx = blockIdx.x * 256 + threadIdx.x;  // < B*S*2D
  int e = idx & (2 * DD - 1);
  int bs = idx >> 10;
  int b = bs >> 7;
  float v = (e < DD) ? sr[(size_t)bs * DD + e] : si[(size_t)bs * DD + e - DD];
  out[idx] = acc[idx] + rem[b] * v;
}

extern "C" void kernel_launch(void* const* d_in, const int* in_sizes, int n_in,
                              void* d_out, int out_size, void* d_ws, size_t ws_size,
                              hipStream_t stream) {
  const float* xr = (const float*)d_in[0];
  const float* xi = (const float*)d_in[1];
  const float* Wl_r = (const float*)d_in[2];
  const float* Wl_i = (const float*)d_in[3];
  const float* Wq_r = (const float*)d_in[4];
  const float* Wq_i = (const float*)d_in[5];
  const float* Wk_r = (const float*)d_in[6];
  const float* Wk_i = (const float*)d_in[7];
  const float* Wv_r = (const float*)d_in[8];
  const float* Wv_i = (const float*)d_in[9];
  const float* ln_scale = (const float*)d_in[10];
  const float* ln_shift = (const float*)d_in[11];
  const float* mod_bias = (const float*)d_in[12];
  const float* gate_mask = (const float*)d_in[13];
  const float* score_w = (const float*)d_in[14];
  const float* score_b = (const float*)d_in[15];
  const float* conf_w = (const float*)d_in[16];
  const float* conf_b = (const float*)d_in[17];
  const float* halt_w = (const float*)d_in[18];
  const float* halt_b = (const float*)d_in[19];
  const float* ctrl_w = (const float*)d_in[20];
  const float* ctrl_b = (const float*)d_in[21];
  const float* st_score_w = (const float*)d_in[22];
  const float* st_score_b = (const float*)d_in[23];
  const float* st_conf_w = (const float*)d_in[24];
  const float* st_conf_b = (const float*)d_in[25];
  float* out = (float*)d_out;

  const int BSD = BB * SS * DD;        // 262144
  const size_t WSLOT = (size_t)MM * DD * 1024;  // u16 per weight matrix

  char* pc = (char*)d_ws;
  float* sr = (float*)pc; pc += (size_t)BSD * 4;
  float* si = (float*)pc; pc += (size_t)BSD * 4;
  float* zr = (float*)pc; pc += (size_t)2 * BMSD * 4;   // 2 split-K partials
  float* zi = (float*)pc; pc += (size_t)2 * BMSD * 4;
  float* prb = (float*)pc; pc += (size_t)BMSD * 4;
  float* pib = (float*)pc; pc += (size_t)BMSD * 4;
  float* scorev = (float*)pc; pc += (size_t)BB * MM * SS * 4;
  float* confv = (float*)pc; pc += (size_t)BB * MM * SS * 4;
  float* haltv = (float*)pc; pc += (size_t)BB * MM * SS * 4;
  float* flat = (float*)pc; pc += (size_t)BB * 2 * DD * 4;
  float* stacc = (float*)pc; pc += 64;
  float* nptrg = (float*)pc; pc += (size_t)BB * KK * 4;
  float* wmg = (float*)pc; pc += (size_t)BB * KK * 4;
  float* memv = (float*)pc; pc += (size_t)BB * KK * 2 * DD * 4;
  float* ptrv = (float*)pc; pc += (size_t)BB * KK * 4;
  float* readv = (float*)pc; pc += (size_t)BB * 2 * DD * 4;
  float* stv = (float*)pc; pc += (size_t)2 * BB * 4;
  float* accb = (float*)pc; pc += (size_t)BB * SS * 2 * DD * 4;
  float* rem = (float*)pc; pc += (size_t)BB * 4;
  float* coeff = (float*)pc; pc += (size_t)BB * 4;
  u16* crbf = (u16*)pc; pc += (size_t)BB * SS * 1024 * 2;
  u16* cibf = (u16*)pc; pc += (size_t)BB * SS * 1024 * 2;
  u16* zbr = (u16*)pc; pc += (size_t)BB * MM * SS * 1024 * 2;
  u16* zbi = (u16*)pc; pc += (size_t)BB * MM * SS * 1024 * 2;
  u16* qbr = (u16*)pc; pc += (size_t)BB * MM * SS * 1024 * 2;  // Y real
  u16* qbi = (u16*)pc; pc += (size_t)BB * MM * SS * 1024 * 2;  // Y imag
  u16* vbr = (u16*)pc; pc += (size_t)BB * MM * SS * 1024 * 2;
  u16* vbi = (u16*)pc; pc += (size_t)BB * MM * SS * 1024 * 2;
  u16* Pb  = (u16*)pc; pc += (size_t)BB * MM * SS * 256 * 2;
  u16* wbf = (u16*)pc; pc += 10 * WSLOT * 2;                   // slots 0,1 Wl; 6,7 Wv; 8,9 H
  u16* wqtr = (u16*)pc; pc += WSLOT * 2;                       // WqT split
  u16* wqti = (u16*)pc; pc += WSLOT * 2;
  u16* wktr = (u16*)pc; pc += WSLOT * 2;                       // WkT split
  u16* wkti = (u16*)pc; pc += WSLOT * 2;
  float* hfr = (float*)pc; pc += (size_t)MM * DD * DD * 4;     // H fp32
  float* hfi = (float*)pc; pc += (size_t)MM * DD * DD * 4;

  // ---- one-time (per launch) weight preprocessing ----
  k_convw<<<4096, 256, 0, stream>>>(Wl_r, wbf + 0 * WSLOT);
  k_convw<<<4096, 256, 0, stream>>>(Wl_i, wbf + 1 * WSLOT);
  k_convw<<<4096, 256, 0, stream>>>(Wv_r, wbf + 6 * WSLOT);
  k_convw<<<4096, 256, 0, stream>>>(Wv_i, wbf + 7 * WSLOT);

  dim3 tgrid(8, 8, 4);
  k_convt<<<tgrid, 256, 0, stream>>>(Wq_r, wqtr);
  k_convt<<<tgrid, 256, 0, stream>>>(Wq_i, wqti);
  k_convt<<<tgrid, 256, 0, stream>>>(Wk_r, wktr);
  k_convt<<<tgrid, 256, 0, stream>>>(Wk_i, wkti);

  // H[e,d] = sum_o conj(WkT[e,o]) * WqT[d,o]
  dim3 hgrid(8, 8, 4);
  k_gemm_g<<<hgrid, 256, 0, stream>>>(wktr, wkti, wqtr, wqti, hfr, hfi);
  k_convw<<<4096, 256, 0, stream>>>(hfr, wbf + 8 * WSLOT);
  k_convw<<<4096, 256, 0, stream>>>(hfi, wbf + 9 * WSLOT);

  k_init<<<2048, 256, 0, stream>>>(xr, xi, sr, si, accb, memv, ptrv, rem, crbf, cibf);

  dim3 ggrid(DD / 64, (BB * SS) / 64, MM * 2);    // 512 blocks (split-K x2)
  dim3 qgrid(MM * 2, DD / 64, (BB * SS) / 64);    // 512 blocks, combo-fastest (XCD = combo)
  dim3 smgrid(1, SS / 64, BB * MM);               // 32 blocks
  dim3 pvgrid(DD / 64, SS / 64, BB * MM);         // 256 blocks

  for (int step = 0; step < NSTEPS; ++step) {
    k_flatctrl<<<BB, 256, 0, stream>>>(sr, si, ctrl_w, ctrl_b, ptrv, flat, nptrg, wmg, stacc,
                                       scorev, confv, haltv);
    k_gemm_mfma<<<ggrid, 256, 0, stream>>>(crbf, cibf, wbf + 0 * WSLOT, wbf + 1 * WSLOT, zr, zi);
    k_lnphase<<<BB * MM * SS, 128, 0, stream>>>(zr, zi, ln_scale, ln_shift, mod_bias, zbr, zbi);
    k_gemm_qkv<<<qgrid, 256, 0, stream>>>(zbr, zbi, wbf, WSLOT, qbr, qbi, vbr, vbi);
    k_scores_sm<<<smgrid, 256, 0, stream>>>(qbr, qbi, zbr, zbi, Pb);
    k_pv<<<pvgrid, 256, 0, stream>>>(Pb, vbr, vbi, gate_mask, score_w, conf_w, halt_w,
                                     prb, pib, scorev, confv, haltv);
    k_memup<<<BB * 4, 256, 0, stream>>>(flat, nptrg, wmg, memv, readv,
                                        st_score_w, st_conf_w, stacc);
    k_haltp<<<BB, 256, 0, stream>>>(haltv, halt_b, rem, coeff, stacc, st_score_b, st_conf_b, stv);
    k_combine<<<BB * SS, 256, 0, stream>>>(prb, pib, scorev, confv, score_b, conf_b,
                                           stv, readv, coeff,
                                           xr, xi, sr, si, accb, crbf, cibf);
  }

  k_final<<<(BB * SS * 2 * DD) / 256, 256, 0, stream>>>(accb, rem, sr, si, out);
}

// Round 8
// 2105.006 us; speedup vs baseline: 1.0783x; 1.0076x over previous
//
#include <hip/hip_runtime.h>

#define DD 512
#define MM 4
#define BB 4
#define SS 128
#define KK 32
#define NSTEPS 16
#define EPSF 1e-6f
#define SCALEF 0.04419417382415922f  // 512^-0.5
#define BMSD (BB * MM * SS * DD)

typedef unsigned short u16;
typedef __bf16 bf16x8 __attribute__((ext_vector_type(8)));
typedef u16 u16x8 __attribute__((ext_vector_type(8)));
typedef float f32x16 __attribute__((ext_vector_type(16)));
typedef unsigned int u32x4 __attribute__((ext_vector_type(4)));

__device__ inline void split_bf16(float x, u16& h, u16& l) {
  __bf16 hb = (__bf16)x;
  float hf = (float)hb;
  __bf16 lb = (__bf16)(x - hf);
  h = __builtin_bit_cast(u16, hb);
  l = __builtin_bit_cast(u16, lb);
}

// ---------------- weight fp32 -> split bf16 [row][1024] (hi | lo) ----------------
__global__ void k_convw(const float* __restrict__ src, u16* __restrict__ dst) {
  int idx = blockIdx.x * 256 + threadIdx.x;  // over M*D*D
  int row = idx >> 9, k = idx & 511;
  u16 h, l;
  split_bf16(src[idx], h, l);
  dst[(size_t)row * 1024 + k] = h;
  dst[(size_t)row * 1024 + 512 + k] = l;
}

// ---------------- transpose-convert: fp32 [m][o][d] -> split bf16 [m*D+d][o hi|lo] ----------------
__global__ void k_convt(const float* __restrict__ src, u16* __restrict__ dst) {
  __shared__ float tile[64][65];
  int m = blockIdx.z;
  int o0 = blockIdx.y * 64, d0 = blockIdx.x * 64;
  int tid = threadIdx.x;  // 256
  int g = tid >> 6, lane = tid & 63;
#pragma unroll
  for (int i = 0; i < 16; i++) {
    int o_l = g * 16 + i;
    tile[o_l][lane] = src[(size_t)(m * 512 + o0 + o_l) * 512 + d0 + lane];
  }
  __syncthreads();
#pragma unroll
  for (int i = 0; i < 16; i++) {
    int d_l = g * 16 + i;
    float v = tile[lane][d_l];
    u16 h, l;
    split_bf16(v, h, l);
    size_t drow = (size_t)(m * 512 + d0 + d_l) * 1024;
    dst[drow + o0 + lane] = h;
    dst[drow + 512 + o0 + lane] = l;
  }
}

// ---------------- init ----------------
__global__ void k_init(const float* __restrict__ xr, const float* __restrict__ xi,
                       float* __restrict__ sr, float* __restrict__ si,
                       float* __restrict__ acc, float* __restrict__ memv,
                       float* __restrict__ ptrv, float* __restrict__ rem,
                       u16* __restrict__ crbf, u16* __restrict__ cibf) {
  int idx = blockIdx.x * 256 + threadIdx.x;
  if (idx < BB * SS * 2 * DD) acc[idx] = 0.f;
  if (idx < BB * SS * DD) {
    float a = xr[idx], b = xi[idx];
    sr[idx] = a; si[idx] = b;
    int row = idx >> 9, d = idx & 511;
    u16 h, l;
    split_bf16(a, h, l);   // c0 = 0.5x + 0.5x = x
    crbf[(size_t)row * 1024 + d] = h;
    crbf[(size_t)row * 1024 + 512 + d] = l;
    split_bf16(b, h, l);
    cibf[(size_t)row * 1024 + d] = h;
    cibf[(size_t)row * 1024 + 512 + d] = l;
  }
  if (idx < BB * KK * 2 * DD) memv[idx] = 0.f;
  if (idx < BB * KK) ptrv[idx] = ((idx & (KK - 1)) == 0) ? 1.f : 0.f;
  if (idx < BB) rem[idx] = 1.f;
}

// ---------------- flat_in + control softmax + ptr update + head-acc zero ----------------
__global__ void k_flatctrl(const float* __restrict__ sr, const float* __restrict__ si,
                           const float* __restrict__ ctrl_w, const float* __restrict__ ctrl_b,
                           float* __restrict__ ptrv, float* __restrict__ flat_in,
                           float* __restrict__ nptrg, float* __restrict__ wmg,
                           float* __restrict__ stacc,
                           float* __restrict__ scorev, float* __restrict__ confv,
                           float* __restrict__ haltv) {
  int b = blockIdx.x;
  int tid = threadIdx.x;  // 256
  __shared__ float red[3 * 256];
  __shared__ float ctrl[3], optr[KK], nptr_s[KK], wm_s[KK], normf;

  if (tid < KK) optr[tid] = ptrv[b * KK + tid];

  // zero head accumulators for this b (k_pv accumulates raw dots atomically)
#pragma unroll
  for (int i = 0; i < 2; i++) {
    int r = b * MM * SS + tid + i * 256;
    scorev[r] = 0.f; confv[r] = 0.f; haltv[r] = 0.f;
  }

  int e4 = tid * 4;
  const float* basep = (e4 < DD) ? sr : si;
  int d4 = (e4 < DD) ? e4 : (e4 - DD);
  float4 accv = make_float4(0.f, 0.f, 0.f, 0.f);
  size_t base = (size_t)b * SS * DD + d4;
  for (int s = 0; s < SS; s++) {
    float4 v = *(const float4*)&basep[base + (size_t)s * DD];
    accv.x += v.x; accv.y += v.y; accv.z += v.z; accv.w += v.w;
  }
  accv.x *= (1.0f / SS); accv.y *= (1.0f / SS); accv.z *= (1.0f / SS); accv.w *= (1.0f / SS);
  *(float4*)&flat_in[b * 2 * DD + e4] = accv;
  float fv[4] = {accv.x, accv.y, accv.z, accv.w};
  float d0 = 0.f, d1 = 0.f, d2 = 0.f;
#pragma unroll
  for (int j = 0; j < 4; j++) {
    d0 += fv[j] * ctrl_w[(e4 + j) * 3 + 0];
    d1 += fv[j] * ctrl_w[(e4 + j) * 3 + 1];
    d2 += fv[j] * ctrl_w[(e4 + j) * 3 + 2];
  }
  red[tid] = d0; red[256 + tid] = d1; red[512 + tid] = d2;
  __syncthreads();
  for (int off = 128; off > 0; off >>= 1) {
    if (tid < off) {
      red[tid] += red[tid + off];
      red[256 + tid] += red[256 + tid + off];
      red[512 + tid] += red[512 + tid + off];
    }
    __syncthreads();
  }
  if (tid == 0) {
    float l0 = red[0] + ctrl_b[0], l1 = red[256] + ctrl_b[1], l2 = red[512] + ctrl_b[2];
    float mx = fmaxf(l0, fmaxf(l1, l2));
    float e0 = expf(l0 - mx), e1 = expf(l1 - mx), e2 = expf(l2 - mx);
    float s = e0 + e1 + e2;
    ctrl[0] = e0 / s; ctrl[1] = e1 / s; ctrl[2] = e2 / s;
    stacc[b * 2] = 0.f; stacc[b * 2 + 1] = 0.f;
  }
  __syncthreads();
  if (tid < KK) {
    float up = optr[(tid + KK - 1) & (KK - 1)];
    float dn = optr[(tid + 1) & (KK - 1)];
    float cu = optr[tid];
    nptr_s[tid] = ctrl[0] * up + ctrl[1] * dn + ctrl[2] * cu;
    wm_s[tid] = ctrl[0] * up;
  }
  __syncthreads();
  if (tid == 0) {
    float s = 0.f;
    for (int k = 0; k < KK; k++) s += nptr_s[k];
    normf = 1.f / (s + EPSF);
  }
  __syncthreads();
  if (tid < KK) {
    float np = nptr_s[tid] * normf;
    ptrv[b * KK + tid] = np;
    nptrg[b * KK + tid] = np;
    wmg[b * KK + tid] = wm_s[tid];
  }
}

#define LSTR 72  // LDS row stride in bf16 elems

// ---------------- Wl complex NT GEMM, split-K x2 (even/odd chunks), fp32 partials ----------------
__global__ __launch_bounds__(256) void k_gemm_mfma(
    const u16* __restrict__ Ar, const u16* __restrict__ Ai,
    const u16* __restrict__ Wr, const u16* __restrict__ Wi,
    float* __restrict__ Cr, float* __restrict__ Ci) {
  __shared__ u16 sAr[64][LSTR], sAi[64][LSTR], sWr[64][LSTR], sWi[64][LSTR];
  int mz = blockIdx.z;
  int m = mz & (MM - 1), split = mz >> 2;
  int row_blk = blockIdx.y * 64, o_blk = blockIdx.x * 64;
  int tid = threadIdx.x;

  int lrow = tid >> 3, lk8 = (tid & 7) << 3;
  size_t arow0 = (size_t)(row_blk + lrow), arow1 = arow0 + 32;  // dense b*S+s rows
  size_t wrow0 = (size_t)m * DD + o_blk + lrow, wrow1 = wrow0 + 32;

  int wave = tid >> 6, lane = tid & 63;
  int wrow = (wave >> 1) * 32, wcol = (wave & 1) * 32;
  int l31 = lane & 31, khalf = (lane >> 5) * 8;

  f32x16 accP, accN, accI;
  for (int i = 0; i < 16; i++) { accP[i] = 0.f; accN[i] = 0.f; accI[i] = 0.f; }

  int it20 = split;
  int seg0 = it20 >> 3, k00 = (it20 & 7) * 64;
  int aofs0 = (seg0 == 1) ? 512 : 0, wofs0 = (seg0 == 2) ? 512 : 0;
  u16x8 g0 = *(const u16x8*)&Ar[arow0 * 1024 + aofs0 + k00 + lk8];
  u16x8 g1 = *(const u16x8*)&Ar[arow1 * 1024 + aofs0 + k00 + lk8];
  u16x8 g2 = *(const u16x8*)&Ai[arow0 * 1024 + aofs0 + k00 + lk8];
  u16x8 g3 = *(const u16x8*)&Ai[arow1 * 1024 + aofs0 + k00 + lk8];
  u16x8 g4 = *(const u16x8*)&Wr[wrow0 * 1024 + wofs0 + k00 + lk8];
  u16x8 g5 = *(const u16x8*)&Wr[wrow1 * 1024 + wofs0 + k00 + lk8];
  u16x8 g6 = *(const u16x8*)&Wi[wrow0 * 1024 + wofs0 + k00 + lk8];
  u16x8 g7 = *(const u16x8*)&Wi[wrow1 * 1024 + wofs0 + k00 + lk8];

  for (int jt = 0; jt < 12; ++jt) {
    __syncthreads();  // prev iter's LDS reads complete
    *(u16x8*)&sAr[lrow][lk8] = g0;
    *(u16x8*)&sAr[lrow + 32][lk8] = g1;
    *(u16x8*)&sAi[lrow][lk8] = g2;
    *(u16x8*)&sAi[lrow + 32][lk8] = g3;
    *(u16x8*)&sWr[lrow][lk8] = g4;
    *(u16x8*)&sWr[lrow + 32][lk8] = g5;
    *(u16x8*)&sWi[lrow][lk8] = g6;
    *(u16x8*)&sWi[lrow + 32][lk8] = g7;
    u16x8 n0, n1, n2, n3, n4, n5, n6, n7;
    if (jt < 11) {
      int it2 = 2 * (jt + 1) + split, seg = it2 >> 3, k0 = (it2 & 7) * 64;
      int aofs = (seg == 1) ? 512 : 0, wofs = (seg == 2) ? 512 : 0;
      n0 = *(const u16x8*)&Ar[arow0 * 1024 + aofs + k0 + lk8];
      n1 = *(const u16x8*)&Ar[arow1 * 1024 + aofs + k0 + lk8];
      n2 = *(const u16x8*)&Ai[arow0 * 1024 + aofs + k0 + lk8];
      n3 = *(const u16x8*)&Ai[arow1 * 1024 + aofs + k0 + lk8];
      n4 = *(const u16x8*)&Wr[wrow0 * 1024 + wofs + k0 + lk8];
      n5 = *(const u16x8*)&Wr[wrow1 * 1024 + wofs + k0 + lk8];
      n6 = *(const u16x8*)&Wi[wrow0 * 1024 + wofs + k0 + lk8];
      n7 = *(const u16x8*)&Wi[wrow1 * 1024 + wofs + k0 + lk8];
    }
    __syncthreads();
#pragma unroll
    for (int kk = 0; kk < 64; kk += 16) {
      bf16x8 fAr = *(const bf16x8*)&sAr[wrow + l31][kk + khalf];
      bf16x8 fAi = *(const bf16x8*)&sAi[wrow + l31][kk + khalf];
      bf16x8 fWr = *(const bf16x8*)&sWr[wcol + l31][kk + khalf];
      bf16x8 fWi = *(const bf16x8*)&sWi[wcol + l31][kk + khalf];
      accP = __builtin_amdgcn_mfma_f32_32x32x16_bf16(fAr, fWr, accP, 0, 0, 0);
      accN = __builtin_amdgcn_mfma_f32_32x32x16_bf16(fAi, fWi, accN, 0, 0, 0);
      accI = __builtin_amdgcn_mfma_f32_32x32x16_bf16(fAi, fWr, accI, 0, 0, 0);
      accI = __builtin_amdgcn_mfma_f32_32x32x16_bf16(fAr, fWi, accI, 0, 0, 0);
    }
    if (jt < 11) {
      g0 = n0; g1 = n1; g2 = n2; g3 = n3; g4 = n4; g5 = n5; g6 = n6; g7 = n7;
    }
  }

  int o = o_blk + wcol + l31;
  size_t sofs = (size_t)split * BMSD;
#pragma unroll
  for (int reg = 0; reg < 16; reg++) {
    int r_in = (reg & 3) + 8 * (reg >> 2) + 4 * (lane >> 5);
    int gr = row_blk + wrow + r_in;
    int b = gr >> 7, s = gr & (SS - 1);
    size_t crow = (size_t)((b * MM + m) * SS + s);
    Cr[sofs + crow * DD + o] = accP[reg] - accN[reg];
    Ci[sofs + crow * DD + o] = accI[reg];
  }
}

// ---------------- one-time: H[e,d] = sum_o conj(WkT[e,o]) * WqT[d,o]  (fp32 out) ----------------
__global__ __launch_bounds__(256) void k_gemm_g(
    const u16* __restrict__ Ar, const u16* __restrict__ Ai,
    const u16* __restrict__ Wr, const u16* __restrict__ Wi,
    float* __restrict__ Hr, float* __restrict__ Hi) {
  __shared__ u16 sAr[64][LSTR], sAi[64][LSTR], sWr[64][LSTR], sWi[64][LSTR];
  int m = blockIdx.z;
  int row_blk = blockIdx.y * 64, o_blk = blockIdx.x * 64;
  int tid = threadIdx.x;

  int lrow = tid >> 3, lk8 = (tid & 7) << 3;
  size_t arow0 = (size_t)(m * 512 + row_blk + lrow), arow1 = arow0 + 32;
  size_t wrow0 = (size_t)(m * 512 + o_blk + lrow), wrow1 = wrow0 + 32;

  int wave = tid >> 6, lane = tid & 63;
  int wrow = (wave >> 1) * 32, wcol = (wave & 1) * 32;
  int l31 = lane & 31, khalf = (lane >> 5) * 8;

  f32x16 accP, accN, accI;
  for (int i = 0; i < 16; i++) { accP[i] = 0.f; accN[i] = 0.f; accI[i] = 0.f; }

  u16x8 g0 = *(const u16x8*)&Ar[arow0 * 1024 + lk8];
  u16x8 g1 = *(const u16x8*)&Ar[arow1 * 1024 + lk8];
  u16x8 g2 = *(const u16x8*)&Ai[arow0 * 1024 + lk8];
  u16x8 g3 = *(const u16x8*)&Ai[arow1 * 1024 + lk8];
  u16x8 g4 = *(const u16x8*)&Wr[wrow0 * 1024 + lk8];
  u16x8 g5 = *(const u16x8*)&Wr[wrow1 * 1024 + lk8];
  u16x8 g6 = *(const u16x8*)&Wi[wrow0 * 1024 + lk8];
  u16x8 g7 = *(const u16x8*)&Wi[wrow1 * 1024 + lk8];

  for (int it = 0; it < 24; ++it) {
    __syncthreads();
    *(u16x8*)&sAr[lrow][lk8] = g0;
    *(u16x8*)&sAr[lrow + 32][lk8] = g1;
    *(u16x8*)&sAi[lrow][lk8] = g2;
    *(u16x8*)&sAi[lrow + 32][lk8] = g3;
    *(u16x8*)&sWr[lrow][lk8] = g4;
    *(u16x8*)&sWr[lrow + 32][lk8] = g5;
    *(u16x8*)&sWi[lrow][lk8] = g6;
    *(u16x8*)&sWi[lrow + 32][lk8] = g7;
    u16x8 n0, n1, n2, n3, n4, n5, n6, n7;
    if (it < 23) {
      int it2 = it + 1, seg = it2 >> 3, k0 = (it2 & 7) * 64;
      int aofs = (seg == 1) ? 512 : 0, wofs = (seg == 2) ? 512 : 0;
      n0 = *(const u16x8*)&Ar[arow0 * 1024 + aofs + k0 + lk8];
      n1 = *(const u16x8*)&Ar[arow1 * 1024 + aofs + k0 + lk8];
      n2 = *(const u16x8*)&Ai[arow0 * 1024 + aofs + k0 + lk8];
      n3 = *(const u16x8*)&Ai[arow1 * 1024 + aofs + k0 + lk8];
      n4 = *(const u16x8*)&Wr[wrow0 * 1024 + wofs + k0 + lk8];
      n5 = *(const u16x8*)&Wr[wrow1 * 1024 + wofs + k0 + lk8];
      n6 = *(const u16x8*)&Wi[wrow0 * 1024 + wofs + k0 + lk8];
      n7 = *(const u16x8*)&Wi[wrow1 * 1024 + wofs + k0 + lk8];
    }
    __syncthreads();
#pragma unroll
    for (int kk = 0; kk < 64; kk += 16) {
      bf16x8 fAr = *(const bf16x8*)&sAr[wrow + l31][kk + khalf];
      bf16x8 fAi = *(const bf16x8*)&sAi[wrow + l31][kk + khalf];
      bf16x8 fWr = *(const bf16x8*)&sWr[wcol + l31][kk + khalf];
      bf16x8 fWi = *(const bf16x8*)&sWi[wcol + l31][kk + khalf];
      u32x4 t = __builtin_bit_cast(u32x4, fAi) ^ 0x80008000u;
      bf16x8 nAi = __builtin_bit_cast(bf16x8, t);
      accP = __builtin_amdgcn_mfma_f32_32x32x16_bf16(fAr, fWr, accP, 0, 0, 0);
      accN = __builtin_amdgcn_mfma_f32_32x32x16_bf16(fAi, fWi, accN, 0, 0, 0);
      accI = __builtin_amdgcn_mfma_f32_32x32x16_bf16(fAr, fWi, accI, 0, 0, 0);
      accI = __builtin_amdgcn_mfma_f32_32x32x16_bf16(nAi, fWr, accI, 0, 0, 0);
    }
    if (it < 23) {
      g0 = n0; g1 = n1; g2 = n2; g3 = n3; g4 = n4; g5 = n5; g6 = n6; g7 = n7;
    }
  }

  int o = o_blk + wcol + l31;
#pragma unroll
  for (int reg = 0; reg < 16; reg++) {
    int r_in = (reg & 3) + 8 * (reg >> 2) + 4 * (lane >> 5);
    int gr = row_blk + wrow + r_in;          // e in [0,512)
    size_t crow = (size_t)(m * 512 + gr);
    Hr[crow * DD + o] = accP[reg] + accN[reg];
    Hi[crow * DD + o] = accI[reg];
  }
}

// ---------------- merged Y / V^T GEMM ----------------
// blockIdx.x = (m,w) combo (fastest -> XCD = combo).
// w=0: Y = z x H (NT), rows b*S, cols d. out qb [row*1024 + d hi|lo].
// w=1: V^T[d,s] = sum_k Wv[d,k] z[s,k] — same NT GEMM with A=Wv, B=z.
//      out vbT [(bm*DD+d)*256 + s hi|lo] — k_pv reads rows contiguously.
__global__ __launch_bounds__(256) void k_gemm_qkv(
    const u16* __restrict__ Az_r, const u16* __restrict__ Az_i,
    const u16* __restrict__ wbf, size_t WSLOT,
    u16* __restrict__ qbr, u16* __restrict__ qbi,
    u16* __restrict__ vbtr, u16* __restrict__ vbti) {
  __shared__ u16 sAr[64][LSTR], sAi[64][LSTR], sWr[64][LSTR], sWi[64][LSTR];
  int zid = blockIdx.x;                          // fastest dim -> XCD = combo
  int m = zid >> 1, w = zid & 1;
  int tid = threadIdx.x;
  int lrow = tid >> 3, lk8 = (tid & 7) << 3;
  int wave = tid >> 6, lane = tid & 63;
  int wrow = (wave >> 1) * 32, wcol = (wave & 1) * 32;
  int l31 = lane & 31, khalf = (lane >> 5) * 8;

  const u16 *Ar, *Ai, *Wr, *Wi;
  size_t ra0, ra1, rw0, rw1;
  if (w == 0) {
    Ar = Az_r; Ai = Az_i;
    Wr = wbf + (size_t)8 * WSLOT; Wi = wbf + (size_t)9 * WSLOT;  // H
    int row_blk = blockIdx.z * 64, o_blk = blockIdx.y * 64;
    int gr0 = row_blk + lrow, gr1 = gr0 + 32;
    ra0 = (size_t)(((gr0 >> 7) * MM + m) * SS + (gr0 & (SS - 1)));
    ra1 = (size_t)(((gr1 >> 7) * MM + m) * SS + (gr1 & (SS - 1)));
    rw0 = (size_t)m * DD + o_blk + lrow; rw1 = rw0 + 32;
  } else {
    Ar = wbf + (size_t)6 * WSLOT; Ai = wbf + (size_t)7 * WSLOT;  // Wv
    Wr = Az_r; Wi = Az_i;
    int d_blk = blockIdx.y * 64;
    int b = blockIdx.z >> 1, s0 = (blockIdx.z & 1) * 64;
    ra0 = (size_t)m * DD + d_blk + lrow; ra1 = ra0 + 32;
    rw0 = (size_t)((b * MM + m) * SS) + s0 + lrow; rw1 = rw0 + 32;
  }

  f32x16 accP, accN, accI;
  for (int i = 0; i < 16; i++) { accP[i] = 0.f; accN[i] = 0.f; accI[i] = 0.f; }

  u16x8 g0 = *(const u16x8*)&Ar[ra0 * 1024 + lk8];
  u16x8 g1 = *(const u16x8*)&Ar[ra1 * 1024 + lk8];
  u16x8 g2 = *(const u16x8*)&Ai[ra0 * 1024 + lk8];
  u16x8 g3 = *(const u16x8*)&Ai[ra1 * 1024 + lk8];
  u16x8 g4 = *(const u16x8*)&Wr[rw0 * 1024 + lk8];
  u16x8 g5 = *(const u16x8*)&Wr[rw1 * 1024 + lk8];
  u16x8 g6 = *(const u16x8*)&Wi[rw0 * 1024 + lk8];
  u16x8 g7 = *(const u16x8*)&Wi[rw1 * 1024 + lk8];

  for (int it = 0; it < 24; ++it) {
    __syncthreads();
    *(u16x8*)&sAr[lrow][lk8] = g0;
    *(u16x8*)&sAr[lrow + 32][lk8] = g1;
    *(u16x8*)&sAi[lrow][lk8] = g2;
    *(u16x8*)&sAi[lrow + 32][lk8] = g3;
    *(u16x8*)&sWr[lrow][lk8] = g4;
    *(u16x8*)&sWr[lrow + 32][lk8] = g5;
    *(u16x8*)&sWi[lrow][lk8] = g6;
    *(u16x8*)&sWi[lrow + 32][lk8] = g7;
    u16x8 n0, n1, n2, n3, n4, n5, n6, n7;
    if (it < 23) {
      int it2 = it + 1, seg = it2 >> 3, k0 = (it2 & 7) * 64;
      int aofs = (seg == 1) ? 512 : 0, wofs = (seg == 2) ? 512 : 0;
      n0 = *(const u16x8*)&Ar[ra0 * 1024 + aofs + k0 + lk8];
      n1 = *(const u16x8*)&Ar[ra1 * 1024 + aofs + k0 + lk8];
      n2 = *(const u16x8*)&Ai[ra0 * 1024 + aofs + k0 + lk8];
      n3 = *(const u16x8*)&Ai[ra1 * 1024 + aofs + k0 + lk8];
      n4 = *(const u16x8*)&Wr[rw0 * 1024 + wofs + k0 + lk8];
      n5 = *(const u16x8*)&Wr[rw1 * 1024 + wofs + k0 + lk8];
      n6 = *(const u16x8*)&Wi[rw0 * 1024 + wofs + k0 + lk8];
      n7 = *(const u16x8*)&Wi[rw1 * 1024 + wofs + k0 + lk8];
    }
    __syncthreads();
#pragma unroll
    for (int kk = 0; kk < 64; kk += 16) {
      bf16x8 fAr = *(const bf16x8*)&sAr[wrow + l31][kk + khalf];
      bf16x8 fAi = *(const bf16x8*)&sAi[wrow + l31][kk + khalf];
      bf16x8 fWr = *(const bf16x8*)&sWr[wcol + l31][kk + khalf];
      bf16x8 fWi = *(const bf16x8*)&sWi[wcol + l31][kk + khalf];
      accP = __builtin_amdgcn_mfma_f32_32x32x16_bf16(fAr, fWr, accP, 0, 0, 0);
      accN = __builtin_amdgcn_mfma_f32_32x32x16_bf16(fAi, fWi, accN, 0, 0, 0);
      accI = __builtin_amdgcn_mfma_f32_32x32x16_bf16(fAi, fWr, accI, 0, 0, 0);
      accI = __builtin_amdgcn_mfma_f32_32x32x16_bf16(fAr, fWi, accI, 0, 0, 0);
    }
    if (it < 23) {
      g0 = n0; g1 = n1; g2 = n2; g3 = n3; g4 = n4; g5 = n5; g6 = n6; g7 = n7;
    }
  }

  if (w == 0) {
    int o = blockIdx.y * 64 + wcol + l31;
#pragma unroll
    for (int reg = 0; reg < 16; reg++) {
      int r_in = (reg & 3) + 8 * (reg >> 2) + 4 * (lane >> 5);
      int gr = blockIdx.z * 64 + wrow + r_in;
      int b = gr >> 7, s = gr & (SS - 1);
      size_t crow = (size_t)((b * MM + m) * SS + s);
      u16 h, l;
      split_bf16(accP[reg] - accN[reg], h, l);
      qbr[crow * 1024 + o] = h;
      qbr[crow * 1024 + 512 + o] = l;
      split_bf16(accI[reg], h, l);
      qbi[crow * 1024 + o] = h;
      qbi[crow * 1024 + 512 + o] = l;
    }
  } else {
    int b = blockIdx.z >> 1;
    int s = (blockIdx.z & 1) * 64 + wcol + l31;
#pragma unroll
    for (int reg = 0; reg < 16; reg++) {
      int r_in = (reg & 3) + 8 * (reg >> 2) + 4 * (lane >> 5);
      int d = blockIdx.y * 64 + wrow + r_in;
      size_t crow = (size_t)((b * MM + m) * DD + d);
      u16 h, l;
      split_bf16(accP[reg] - accN[reg], h, l);     // imag of V uses accI below; real here
      vbtr[crow * 256 + s] = h;
      vbtr[crow * 256 + 128 + s] = l;
      split_bf16(accI[reg], h, l);
      vbti[crow * 256 + s] = h;
      vbti[crow * 256 + 128 + s] = l;
    }
  }
}

// ---------------- scores + fused softmax -> split P (reg-prefetch pipelined) ----------------
// Q inputs = Y buffers; K inputs = z buffers (H-folded attention).
__global__ __launch_bounds__(256) void k_scores_sm(
    const u16* __restrict__ Q_r, const u16* __restrict__ Q_i,
    const u16* __restrict__ K_r, const u16* __restrict__ K_i,
    u16* __restrict__ Pb) {
  __shared__ __align__(16) char smem[55296];  // 54 KB
  u16 (*sQr)[LSTR] = (u16(*)[LSTR])smem;                  // 64 rows
  u16 (*sQi)[LSTR] = (u16(*)[LSTR])(smem + 9216);         // 64 rows
  u16 (*sKr)[LSTR] = (u16(*)[LSTR])(smem + 18432);        // 128 rows
  u16 (*sKi)[LSTR] = (u16(*)[LSTR])(smem + 36864);        // 128 rows
  float (*stile)[132] = (float(*)[132])smem;              // 64 x 132 overlay (33792 B)

  int bm = blockIdx.z;
  int s_blk = blockIdx.y * 64;
  int tid = threadIdx.x;
  int lrow = tid >> 3, lk8 = (tid & 7) << 3;
  size_t qrow0 = (size_t)(bm * SS + s_blk + lrow), qrow1 = qrow0 + 32;
  size_t krow = (size_t)(bm * SS + lrow);  // +0,32,64,96

  int wave = tid >> 6, lane = tid & 63;
  int srow_w = (wave & 1) * 32;
  int tcol_w = (wave >> 1) * 64;
  int l31 = lane & 31, khalf = (lane >> 5) * 8;

  f32x16 acc0, acc1;
  for (int i = 0; i < 16; i++) { acc0[i] = 0.f; acc1[i] = 0.f; }

  // prologue loads (it=0)
  u16x8 pf[12];
  pf[0] = *(const u16x8*)&Q_r[qrow0 * 1024 + lk8];
  pf[1] = *(const u16x8*)&Q_r[qrow1 * 1024 + lk8];
  pf[2] = *(const u16x8*)&Q_i[qrow0 * 1024 + lk8];
  pf[3] = *(const u16x8*)&Q_i[qrow1 * 1024 + lk8];
#pragma unroll
  for (int q = 0; q < 4; q++) {
    pf[4 + q] = *(const u16x8*)&K_r[(krow + q * 32) * 1024 + lk8];
    pf[8 + q] = *(const u16x8*)&K_i[(krow + q * 32) * 1024 + lk8];
  }

  for (int it = 0; it < 24; ++it) {
    __syncthreads();  // prev iter's LDS reads complete
    *(u16x8*)&sQr[lrow][lk8] = pf[0];
    *(u16x8*)&sQr[lrow + 32][lk8] = pf[1];
    *(u16x8*)&sQi[lrow][lk8] = pf[2];
    *(u16x8*)&sQi[lrow + 32][lk8] = pf[3];
#pragma unroll
    for (int q = 0; q < 4; q++) {
      *(u16x8*)&sKr[lrow + q * 32][lk8] = pf[4 + q];
      *(u16x8*)&sKi[lrow + q * 32][lk8] = pf[8 + q];
    }
    // issue next iter's loads BEFORE compute
    u16x8 nf[12];
    if (it < 23) {
      int it2 = it + 1, seg = it2 >> 3, k0 = (it2 & 7) * 64;
      int qofs = (seg == 1) ? 512 : 0;
      int kofs = (seg == 2) ? 512 : 0;
      nf[0] = *(const u16x8*)&Q_r[qrow0 * 1024 + qofs + k0 + lk8];
      nf[1] = *(const u16x8*)&Q_r[qrow1 * 1024 + qofs + k0 + lk8];
      nf[2] = *(const u16x8*)&Q_i[qrow0 * 1024 + qofs + k0 + lk8];
      nf[3] = *(const u16x8*)&Q_i[qrow1 * 1024 + qofs + k0 + lk8];
#pragma unroll
      for (int q = 0; q < 4; q++) {
        nf[4 + q] = *(const u16x8*)&K_r[(krow + q * 32) * 1024 + kofs + k0 + lk8];
        nf[8 + q] = *(const u16x8*)&K_i[(krow + q * 32) * 1024 + kofs + k0 + lk8];
      }
    }
    __syncthreads();
#pragma unroll
    for (int kk = 0; kk < 64; kk += 16) {
      bf16x8 fQr = *(const bf16x8*)&sQr[srow_w + l31][kk + khalf];
      bf16x8 fQi = *(const bf16x8*)&sQi[srow_w + l31][kk + khalf];
      bf16x8 fKr0 = *(const bf16x8*)&sKr[tcol_w + l31][kk + khalf];
      bf16x8 fKr1 = *(const bf16x8*)&sKr[tcol_w + 32 + l31][kk + khalf];
      bf16x8 fKi0 = *(const bf16x8*)&sKi[tcol_w + l31][kk + khalf];
      bf16x8 fKi1 = *(const bf16x8*)&sKi[tcol_w + 32 + l31][kk + khalf];
      acc0 = __builtin_amdgcn_mfma_f32_32x32x16_bf16(fQr, fKr0, acc0, 0, 0, 0);
      acc0 = __builtin_amdgcn_mfma_f32_32x32x16_bf16(fQi, fKi0, acc0, 0, 0, 0);
      acc1 = __builtin_amdgcn_mfma_f32_32x32x16_bf16(fQr, fKr1, acc1, 0, 0, 0);
      acc1 = __builtin_amdgcn_mfma_f32_32x32x16_bf16(fQi, fKi1, acc1, 0, 0, 0);
    }
    if (it < 23) {
#pragma unroll
      for (int j = 0; j < 12; j++) pf[j] = nf[j];
    }
  }

  // ---- fused softmax over full 128-col rows ----
  __syncthreads();  // staging tiles dead; overlay stile
#pragma unroll
  for (int reg = 0; reg < 16; reg++) {
    int r = srow_w + (reg & 3) + 8 * (reg >> 2) + 4 * (lane >> 5);
    stile[r][tcol_w + l31] = acc0[reg] * SCALEF;
    stile[r][tcol_w + 32 + l31] = acc1[reg] * SCALEF;
  }
  __syncthreads();
  int row = tid >> 2;          // 0..63
  int quarter = tid & 3;       // cols quarter*32..+31
  float mx = -3.4e38f;
#pragma unroll
  for (int j = 0; j < 32; j++) mx = fmaxf(mx, stile[row][quarter * 32 + j]);
  mx = fmaxf(mx, __shfl_xor(mx, 1));
  mx = fmaxf(mx, __shfl_xor(mx, 2));
  float ev[32];
  float sum = 0.f;
#pragma unroll
  for (int j = 0; j < 32; j++) {
    ev[j] = expf(stile[row][quarter * 32 + j] - mx);
    sum += ev[j];
  }
  sum += __shfl_xor(sum, 1);
  sum += __shfl_xor(sum, 2);
  float inv = 1.f / sum;
  size_t prow = (size_t)(bm * SS + s_blk + row) * 256;
#pragma unroll
  for (int j = 0; j < 32; j++) {
    int c = quarter * 32 + j;
    u16 h, l;
    split_bf16(ev[j] * inv, h, l);
    Pb[prow + c] = h;
    Pb[prow + 128 + c] = l;
  }
}

// ---------------- P x V^T MFMA + gate -> pr/pi fp32, FUSED score/conf/halt head dots ----------
// V^T rows (d) read contiguously — no transpose-on-read scalar LDS ops.
__global__ __launch_bounds__(256) void k_pv(
    const u16* __restrict__ Pb, const u16* __restrict__ vbtr, const u16* __restrict__ vbti,
    const float* __restrict__ gate_mask,
    const float* __restrict__ score_w, const float* __restrict__ conf_w,
    const float* __restrict__ halt_w,
    float* __restrict__ pr, float* __restrict__ pi,
    float* __restrict__ scorev, float* __restrict__ confv, float* __restrict__ haltv) {
  __shared__ u16 sP[64][LSTR], sVr[64][LSTR], sVi[64][LSTR];
  int bm = blockIdx.z;
  int m = bm & (MM - 1);
  int s_blk = blockIdx.y * 64;
  int o_blk = blockIdx.x * 64;
  int tid = threadIdx.x;
  int lrow = tid >> 3, lk8 = (tid & 7) << 3;
  size_t prow0 = (size_t)(bm * SS + s_blk + lrow), prow1 = prow0 + 32;
  size_t vrow0 = (size_t)(bm * DD + o_blk + lrow), vrow1 = vrow0 + 32;  // V^T rows (d)

  int wave = tid >> 6, lane = tid & 63;
  int wrow = (wave >> 1) * 32;   // s
  int wcol = (wave & 1) * 32;    // d
  int l31 = lane & 31, khalf = (lane >> 5) * 8;

  f32x16 accR, accI;
  for (int i = 0; i < 16; i++) { accR[i] = 0.f; accI[i] = 0.f; }

  for (int it = 0; it < 6; ++it) {
    int seg = it >> 1, k0 = (it & 1) * 64;        // t-chunk
    int pofs = (seg == 1) ? 128 : 0;              // P lo half for seg1
    int vofs = (seg == 2) ? 128 : 0;              // V^T lo half for seg2 (row len 256)
    u16x8 p0 = *(const u16x8*)&Pb[prow0 * 256 + pofs + k0 + lk8];
    u16x8 p1 = *(const u16x8*)&Pb[prow1 * 256 + pofs + k0 + lk8];
    u16x8 v0 = *(const u16x8*)&vbtr[vrow0 * 256 + vofs + k0 + lk8];
    u16x8 v1 = *(const u16x8*)&vbtr[vrow1 * 256 + vofs + k0 + lk8];
    u16x8 w0 = *(const u16x8*)&vbti[vrow0 * 256 + vofs + k0 + lk8];
    u16x8 w1 = *(const u16x8*)&vbti[vrow1 * 256 + vofs + k0 + lk8];
    __syncthreads();
    *(u16x8*)&sP[lrow][lk8] = p0;
    *(u16x8*)&sP[lrow + 32][lk8] = p1;
    *(u16x8*)&sVr[lrow][lk8] = v0;
    *(u16x8*)&sVr[lrow + 32][lk8] = v1;
    *(u16x8*)&sVi[lrow][lk8] = w0;
    *(u16x8*)&sVi[lrow + 32][lk8] = w1;
    __syncthreads();
#pragma unroll
    for (int kk = 0; kk < 64; kk += 16) {
      bf16x8 fP = *(const bf16x8*)&sP[wrow + l31][kk + khalf];
      bf16x8 fVr = *(const bf16x8*)&sVr[wcol + l31][kk + khalf];
      bf16x8 fVi = *(const bf16x8*)&sVi[wcol + l31][kk + khalf];
      accR = __builtin_amdgcn_mfma_f32_32x32x16_bf16(fP, fVr, accR, 0, 0, 0);
      accI = __builtin_amdgcn_mfma_f32_32x32x16_bf16(fP, fVi, accI, 0, 0, 0);
    }
  }

  int d = o_blk + wcol + l31;
  float g = 1.f / (1.f + expf(-gate_mask[m * DD + d]));
  // head weight slices for this (m, d)
  float swr = score_w[m * 2 * DD + d], swi = score_w[m * 2 * DD + DD + d];
  float cwr = conf_w[m * 2 * DD + d],  cwi = conf_w[m * 2 * DD + DD + d];
  float hwr = halt_w[m * 2 * DD + d],  hwi = halt_w[m * 2 * DD + DD + d];
#pragma unroll
  for (int reg = 0; reg < 16; reg++) {
    int r_in = (reg & 3) + 8 * (reg >> 2) + 4 * (lane >> 5);
    size_t crow = (size_t)(bm * SS + s_blk + wrow + r_in);
    float vR = accR[reg] * g, vI = accI[reg] * g;
    pr[crow * DD + d] = vR;
    pi[crow * DD + d] = vI;
    // per-row head dot partials over this wave's 32 d-lanes
    float ps = vR * swr + vI * swi;
    float pc = vR * cwr + vI * cwi;
    float ph = vR * hwr + vI * hwi;
#pragma unroll
    for (int off = 1; off < 32; off <<= 1) {
      ps += __shfl_xor(ps, off);
      pc += __shfl_xor(pc, off);
      ph += __shfl_xor(ph, off);
    }
    if (l31 == 0) {
      atomicAdd(&scorev[crow], ps);
      atomicAdd(&confv[crow], pc);
      atomicAdd(&haltv[crow], ph);
    }
  }
}

// ---------------- magnitude LN + phase renorm + mod scale -> split bf16 ----------------
// zr/zi carry TWO split-K partials at stride BMSD; summed here.
__global__ void k_lnphase(const float* __restrict__ zr, const float* __restrict__ zi,
                          const float* __restrict__ ln_scale, const float* __restrict__ ln_shift,
                          const float* __restrict__ mod_bias,
                          u16* __restrict__ zbr, u16* __restrict__ zbi) {
  int row = blockIdx.x;            // (b*M+m)*S + s
  int m = (row >> 7) & (MM - 1);
  int tid = threadIdx.x;           // 128
  size_t base = (size_t)row * DD;
  float zrv[4], ziv[4], rv[4];
  float sum = 0.f, sumsq = 0.f;
#pragma unroll
  for (int i = 0; i < 4; i++) {
    int o = tid + i * 128;
    float a = zr[base + o] + zr[(size_t)BMSD + base + o];
    float bv = zi[base + o] + zi[(size_t)BMSD + base + o];
    zrv[i] = a; ziv[i] = bv;
    float r = sqrtf(a * a + bv * bv);
    rv[i] = r;
    float mg = r + EPSF;
    sum += mg;
    sumsq += mg * mg;
  }
  __shared__ float rs[128], rq[128];
  rs[tid] = sum; rq[tid] = sumsq;
  __syncthreads();
  for (int off = 64; off > 0; off >>= 1) {
    if (tid < off) { rs[tid] += rs[tid + off]; rq[tid] += rq[tid + off]; }
    __syncthreads();
  }
  float mean = rs[0] * (1.0f / DD);
  float var = (rq[0] - (float)DD * mean * mean) * (1.0f / (DD - 1));
  float inv = 1.0f / sqrtf(var + EPSF);
#pragma unroll
  for (int i = 0; i < 4; i++) {
    int o = tid + i * 128;
    float mg = rv[i] + EPSF;
    float nm = (mg - mean) * inv * ln_scale[m * DD + o] + ln_shift[m * DD + o];
    float r = rv[i];
    float cosp, sinp;
    if (r > 0.f) { cosp = zrv[i] / r; sinp = ziv[i] / r; }
    else { cosp = 1.f; sinp = 0.f; }
    float z1r = nm * cosp, z1i = nm * sinp;
    float nrm = sqrtf(z1r * z1r + z1i * z1i) + EPSF;
    float sc = fmaxf(nrm + mod_bias[m * DD + o], 0.f) / nrm;
    u16 h, l;
    split_bf16(z1r * sc, h, l);
    zbr[(size_t)row * 1024 + o] = h;
    zbr[(size_t)row * 1024 + 512 + o] = l;
    split_bf16(z1i * sc, h, l);
    zbi[(size_t)row * 1024 + o] = h;
    zbi[(size_t)row * 1024 + 512 + o] = l;
  }
}

// ---------------- stack mem update + read + st dot partials ----------------
__global__ void k_memup(const float* __restrict__ flat_in,
                        const float* __restrict__ nptrg, const float* __restrict__ wmg,
                        float* __restrict__ memv, float* __restrict__ readv,
                        const float* __restrict__ st_score_w, const float* __restrict__ st_conf_w,
                        float* __restrict__ stacc) {
  int b = blockIdx.x >> 2;
  int chunk = blockIdx.x & 3;
  int tid = threadIdx.x;           // 256
  int e = chunk * 256 + tid;       // 0..1023
  __shared__ float nptr[KK], wm[KK];
  __shared__ float red[256], red2[256];
  if (tid < KK) { nptr[tid] = nptrg[b * KK + tid]; wm[tid] = wmg[b * KK + tid]; }
  __syncthreads();
  float fl = flat_in[b * 2 * DD + e];
  float racc = 0.f;
#pragma unroll
  for (int k = 0; k < KK; k++) {
    size_t idx = ((size_t)(b * KK + k)) * 2 * DD + e;
    float nm = wm[k] * fl + memv[idx] * (1.f - wm[k]);
    memv[idx] = nm;
    racc += nm * nptr[k];
  }
  readv[b * 2 * DD + e] = racc;
  red[tid] = racc * st_score_w[e];
  red2[tid] = racc * st_conf_w[e];
  __syncthreads();
  for (int off = 128; off > 0; off >>= 1) {
    if (tid < off) { red[tid] += red[tid + off]; red2[tid] += red2[tid + off]; }
    __syncthreads();
  }
  if (tid == 0) {
    atomicAdd(&stacc[b * 2], red[0]);
    atomicAdd(&stacc[b * 2 + 1], red2[0]);
  }
}

// ---------------- halt p + stv finalize (halt bias applied here; haltv is raw dot) ----------------
__global__ void k_haltp(const float* __restrict__ halt, const float* __restrict__ halt_b,
                        float* __restrict__ rem,
                        float* __restrict__ coeff, const float* __restrict__ stacc,
                        const float* __restrict__ st_score_b, const float* __restrict__ st_conf_b,
                        float* __restrict__ stv) {
  int b = blockIdx.x;
  int tid = threadIdx.x;  // 256
  __shared__ float red[256];
  float v0 = halt[b * MM * SS + tid] + halt_b[tid >> 7];
  float v1 = halt[b * MM * SS + 256 + tid] + halt_b[(tid + 256) >> 7];
  red[tid] = 1.f / (1.f + expf(-v0)) + 1.f / (1.f + expf(-v1));
  __syncthreads();
  for (int off = 128; off > 0; off >>= 1) {
    if (tid < off) red[tid] += red[tid + off];
    __syncthreads();
  }
  if (tid == 0) {
    float p = red[0] * (1.0f / (MM * SS));
    float r = rem[b];
    coeff[b] = p * r;
    rem[b] = r * (1.f - p);
    stv[b] = stacc[b * 2] + st_score_b[0];
    stv[BB + b] = 1.f / (1.f + expf(-(stacc[b * 2 + 1] + st_conf_b[0])));
  }
}

// ---------------- module-mix softmax + new state + acc + next-step c ----------------
// score/conf inputs are raw dots; biases + sigmoid applied here.
__global__ void k_combine(const float* __restrict__ pr, const float* __restrict__ pi,
                          const float* __restrict__ score, const float* __restrict__ conf,
                          const float* __restrict__ score_b, const float* __restrict__ conf_b,
                          const float* __restrict__ stv, const float* __restrict__ readv,
                          const float* __restrict__ coeff,
                          const float* __restrict__ xr, const float* __restrict__ xi,
                          float* __restrict__ sr, float* __restrict__ si, float* __restrict__ acc,
                          u16* __restrict__ crbf, u16* __restrict__ cibf) {
  int bs = blockIdx.x;             // b*S + s
  int b = bs >> 7, s = bs & (SS - 1);
  int tid = threadIdx.x;           // 256
  __shared__ float w[5];
  if (tid == 0) {
    float l[5];
    for (int m = 0; m < MM; m++) {
      int r = (b * MM + m) * SS + s;
      float sc = score[r] + score_b[m];
      float cf = 1.f / (1.f + expf(-(conf[r] + conf_b[m])));
      l[m] = sc * cf;
    }
    l[4] = stv[b] * stv[BB + b];
    float mx = l[0];
    for (int j = 1; j < 5; j++) mx = fmaxf(mx, l[j]);
    float sum = 0.f;
    for (int j = 0; j < 5; j++) { l[j] = expf(l[j] - mx); sum += l[j]; }
    for (int j = 0; j < 5; j++) w[j] = l[j] / sum;
  }
  __syncthreads();
  float cf = coeff[b];
#pragma unroll
  for (int i = 0; i < 2; i++) {
    int d = tid + i * 256;
    float nsr = w[4] * readv[b * 2 * DD + d];
    float nsi = w[4] * readv[b * 2 * DD + DD + d];
#pragma unroll
    for (int m = 0; m < MM; m++) {
      size_t off = ((size_t)((b * MM + m) * SS + s)) * DD + d;
      nsr += w[m] * pr[off];
      nsi += w[m] * pi[off];
    }
    size_t sidx = (size_t)bs * DD + d;
    sr[sidx] = nsr;
    si[sidx] = nsi;
    size_t aoff = (size_t)bs * 2 * DD;
    acc[aoff + d] += cf * nsr;
    acc[aoff + DD + d] += cf * nsi;
    u16 h, l;
    split_bf16(0.5f * xr[sidx] + 0.5f * nsr, h, l);
    crbf[(size_t)bs * 1024 + d] = h;
    crbf[(size_t)bs * 1024 + 512 + d] = l;
    split_bf16(0.5f * xi[sidx] + 0.5f * nsi, h, l);
    cibf[(size_t)bs * 1024 + d] = h;
    cibf[(size_t)bs * 1024 + 512 + d] = l;
  }
}

// ---------------- out = acc + rem * concat(sr, si) ----------------
__global__ void k_final(const float* __restrict__ acc, const float* __restrict__ rem,
                        const float* __restrict__ sr, const float* __restrict__ si,
                        float* __restrict__ out) {
  int idx = blockIdx.x * 256 + threadIdx.x;  // < B*S*2D
  int e = idx & (2 * DD - 1);
  int bs = idx >> 10;
  int b = bs >> 7;
  float v = (e < DD) ? sr[(size_t)bs * DD + e] : si[(size_t)bs * DD + e - DD];
  out[idx] = acc[idx] + rem[b] * v;
}

extern "C" void kernel_launch(void* const* d_in, const int* in_sizes, int n_in,
                              void* d_out, int out_size, void* d_ws, size_t ws_size,
                              hipStream_t stream) {
  const float* xr = (const float*)d_in[0];
  const float* xi = (const float*)d_in[1];
  const float* Wl_r = (const float*)d_in[2];
  const float* Wl_i = (const float*)d_in[3];
  const float* Wq_r = (const float*)d_in[4];
  const float* Wq_i = (const float*)d_in[5];
  const float* Wk_r = (const float*)d_in[6];
  const float* Wk_i = (const float*)d_in[7];
  const float* Wv_r = (const float*)d_in[8];
  const float* Wv_i = (const float*)d_in[9];
  const float* ln_scale = (const float*)d_in[10];
  const float* ln_shift = (const float*)d_in[11];
  const float* mod_bias = (const float*)d_in[12];
  const float* gate_mask = (const float*)d_in[13];
  const float* score_w = (const float*)d_in[14];
  const float* score_b = (const float*)d_in[15];
  const float* conf_w = (const float*)d_in[16];
  const float* conf_b = (const float*)d_in[17];
  const float* halt_w = (const float*)d_in[18];
  const float* halt_b = (const float*)d_in[19];
  const float* ctrl_w = (const float*)d_in[20];
  const float* ctrl_b = (const float*)d_in[21];
  const float* st_score_w = (const float*)d_in[22];
  const float* st_score_b = (const float*)d_in[23];
  const float* st_conf_w = (const float*)d_in[24];
  const float* st_conf_b = (const float*)d_in[25];
  float* out = (float*)d_out;

  const int BSD = BB * SS * DD;        // 262144
  const size_t WSLOT = (size_t)MM * DD * 1024;  // u16 per weight matrix

  char* pc = (char*)d_ws;
  float* sr = (float*)pc; pc += (size_t)BSD * 4;
  float* si = (float*)pc; pc += (size_t)BSD * 4;
  float* zr = (float*)pc; pc += (size_t)2 * BMSD * 4;   // 2 split-K partials
  float* zi = (float*)pc; pc += (size_t)2 * BMSD * 4;
  float* prb = (float*)pc; pc += (size_t)BMSD * 4;
  float* pib = (float*)pc; pc += (size_t)BMSD * 4;
  float* scorev = (float*)pc; pc += (size_t)BB * MM * SS * 4;
  float* confv = (float*)pc; pc += (size_t)BB * MM * SS * 4;
  float* haltv = (float*)pc; pc += (size_t)BB * MM * SS * 4;
  float* flat = (float*)pc; pc += (size_t)BB * 2 * DD * 4;
  float* stacc = (float*)pc; pc += 64;
  float* nptrg = (float*)pc; pc += (size_t)BB * KK * 4;
  float* wmg = (float*)pc; pc += (size_t)BB * KK * 4;
  float* memv = (float*)pc; pc += (size_t)BB * KK * 2 * DD * 4;
  float* ptrv = (float*)pc; pc += (size_t)BB * KK * 4;
  float* readv = (float*)pc; pc += (size_t)BB * 2 * DD * 4;
  float* stv = (float*)pc; pc += (size_t)2 * BB * 4;
  float* accb = (float*)pc; pc += (size_t)BB * SS * 2 * DD * 4;
  float* rem = (float*)pc; pc += (size_t)BB * 4;
  float* coeff = (float*)pc; pc += (size_t)BB * 4;
  u16* crbf = (u16*)pc; pc += (size_t)BB * SS * 1024 * 2;
  u16* cibf = (u16*)pc; pc += (size_t)BB * SS * 1024 * 2;
  u16* zbr = (u16*)pc; pc += (size_t)BB * MM * SS * 1024 * 2;
  u16* zbi = (u16*)pc; pc += (size_t)BB * MM * SS * 1024 * 2;
  u16* qbr = (u16*)pc; pc += (size_t)BB * MM * SS * 1024 * 2;  // Y real
  u16* qbi = (u16*)pc; pc += (size_t)BB * MM * SS * 1024 * 2;  // Y imag
  u16* vbtr = (u16*)pc; pc += (size_t)BB * MM * DD * 256 * 2;  // V^T real [bm*D+d][s hi|lo]
  u16* vbti = (u16*)pc; pc += (size_t)BB * MM * DD * 256 * 2;  // V^T imag
  u16* Pb  = (u16*)pc; pc += (size_t)BB * MM * SS * 256 * 2;
  u16* wbf = (u16*)pc; pc += 10 * WSLOT * 2;                   // slots 0,1 Wl; 6,7 Wv; 8,9 H
  u16* wqtr = (u16*)pc; pc += WSLOT * 2;                       // WqT split
  u16* wqti = (u16*)pc; pc += WSLOT * 2;
  u16* wktr = (u16*)pc; pc += WSLOT * 2;                       // WkT split
  u16* wkti = (u16*)pc; pc += WSLOT * 2;
  float* hfr = (float*)pc; pc += (size_t)MM * DD * DD * 4;     // H fp32
  float* hfi = (float*)pc; pc += (size_t)MM * DD * DD * 4;

  // ---- one-time (per launch) weight preprocessing ----
  k_convw<<<4096, 256, 0, stream>>>(Wl_r, wbf + 0 * WSLOT);
  k_convw<<<4096, 256, 0, stream>>>(Wl_i, wbf + 1 * WSLOT);
  k_convw<<<4096, 256, 0, stream>>>(Wv_r, wbf + 6 * WSLOT);
  k_convw<<<4096, 256, 0, stream>>>(Wv_i, wbf + 7 * WSLOT);

  dim3 tgrid(8, 8, 4);
  k_convt<<<tgrid, 256, 0, stream>>>(Wq_r, wqtr);
  k_convt<<<tgrid, 256, 0, stream>>>(Wq_i, wqti);
  k_convt<<<tgrid, 256, 0, stream>>>(Wk_r, wktr);
  k_convt<<<tgrid, 256, 0, stream>>>(Wk_i, wkti);

  // H[e,d] = sum_o conj(WkT[e,o]) * WqT[d,o]
  dim3 hgrid(8, 8, 4);
  k_gemm_g<<<hgrid, 256, 0, stream>>>(wktr, wkti, wqtr, wqti, hfr, hfi);
  k_convw<<<4096, 256, 0, stream>>>(hfr, wbf + 8 * WSLOT);
  k_convw<<<4096, 256, 0, stream>>>(hfi, wbf + 9 * WSLOT);

  k_init<<<2048, 256, 0, stream>>>(xr, xi, sr, si, accb, memv, ptrv, rem, crbf, cibf);

  dim3 ggrid(DD / 64, (BB * SS) / 64, MM * 2);    // 512 blocks (split-K x2)
  dim3 qgrid(MM * 2, 8, 8);                       // 512 blocks, combo-fastest (XCD = combo)
  dim3 smgrid(1, SS / 64, BB * MM);               // 32 blocks
  dim3 pvgrid(DD / 64, SS / 64, BB * MM);         // 256 blocks

  for (int step = 0; step < NSTEPS; ++step) {
    k_flatctrl<<<BB, 256, 0, stream>>>(sr, si, ctrl_w, ctrl_b, ptrv, flat, nptrg, wmg, stacc,
                                       scorev, confv, haltv);
    k_gemm_mfma<<<ggrid, 256, 0, stream>>>(crbf, cibf, wbf + 0 * WSLOT, wbf + 1 * WSLOT, zr, zi);
    k_lnphase<<<BB * MM * SS, 128, 0, stream>>>(zr, zi, ln_scale, ln_shift, mod_bias, zbr, zbi);
    k_gemm_qkv<<<qgrid, 256, 0, stream>>>(zbr, zbi, wbf, WSLOT, qbr, qbi, vbtr, vbti);
    k_scores_sm<<<smgrid, 256, 0, stream>>>(qbr, qbi, zbr, zbi, Pb);
    k_pv<<<pvgrid, 256, 0, stream>>>(Pb, vbtr, vbti, gate_mask, score_w, conf_w, halt_w,
                                     prb, pib, scorev, confv, haltv);
    k_memup<<<BB * 4, 256, 0, stream>>>(flat, nptrg, wmg, memv, readv,
                                        st_score_w, st_conf_w, stacc);
    k_haltp<<<BB, 256, 0, stream>>>(haltv, halt_b, rem, coeff, stacc, st_score_b, st_conf_b, stv);
    k_combine<<<BB * SS, 256, 0, stream>>>(prb, pib, scorev, confv, score_b, conf_b,
                                           stv, readv, coeff,
                                           xr, xi, sr, si, accb, crbf, cibf);
  }

  k_final<<<(BB * SS * 2 * DD) / 256, 256, 0, stream>>>(accb, rem, sr, si, out);
}